// Round 5
// baseline (1632.261 us; speedup 1.0000x reference)
//
#include <hip/hip_runtime.h>
#include <math.h>

#define N_NODES 100000
#define IN_DIM 64
#define HID 128
#define HID2 64
#define N_EDGES 1600000
#define BN_EPS 1e-5f

// bucketing: 128 dst nodes per bucket
#define NPB 128
#define NB 782            // ceil(100000/128)
#define BIN_BLOCKS 391
#define BIN_CHUNK 4096    // 391*4096 >= 1.6M

// ---------------------------------------------------------------------------
// Binning pass 1: per-block bucket histogram; reserve per-(block,bucket) space
// ---------------------------------------------------------------------------
__global__ __launch_bounds__(256) void bin_count(
    const int* __restrict__ dst,
    int* __restrict__ bucketTotal,     // [NB] (zeroed)
    int* __restrict__ perBlockBase)    // [BIN_BLOCKS*NB]
{
    __shared__ int cnt[NB];
    const int t = threadIdx.x;
    for (int i = t; i < NB; i += 256) cnt[i] = 0;
    __syncthreads();
    const int e0 = blockIdx.x * BIN_CHUNK;
    for (int i = t; i < BIN_CHUNK; i += 256) {
        int e = e0 + i;
        if (e < N_EDGES) atomicAdd(&cnt[dst[e] >> 7], 1);
    }
    __syncthreads();
    for (int b = t; b < NB; b += 256) {
        int c = cnt[b];
        if (c) perBlockBase[blockIdx.x * NB + b] = atomicAdd(&bucketTotal[b], c);
    }
}

// ---------------------------------------------------------------------------
// Binning pass 2: exclusive scan of the 782 bucket totals (one block)
// ---------------------------------------------------------------------------
__global__ __launch_bounds__(1024) void bucket_scan(
    const int* __restrict__ bucketTotal, int* __restrict__ bucketStart)
{
    __shared__ int s[1024];
    const int t = threadIdx.x;
    int v = (t < NB) ? bucketTotal[t] : 0;
    s[t] = v;
    __syncthreads();
    #pragma unroll
    for (int off = 1; off < 1024; off <<= 1) {
        int u = (t >= off) ? s[t - off] : 0;
        __syncthreads();
        s[t] += u;
        __syncthreads();
    }
    if (t < NB) bucketStart[t] = s[t] - v;
    if (t == 0) bucketStart[NB] = N_EDGES;
}

// ---------------------------------------------------------------------------
// Binning pass 3: write packed (src<<7 | localDst) into bucket-grouped order
// ---------------------------------------------------------------------------
__global__ __launch_bounds__(256) void bin_write(
    const int* __restrict__ src, const int* __restrict__ dst,
    const int* __restrict__ bucketStart,
    const int* __restrict__ perBlockBase,
    unsigned int* __restrict__ binned)   // [E]
{
    __shared__ int cur[NB];
    const int t = threadIdx.x;
    for (int i = t; i < NB; i += 256) cur[i] = 0;
    __syncthreads();
    const int e0 = blockIdx.x * BIN_CHUNK;
    for (int i = t; i < BIN_CHUNK; i += 256) {
        int e = e0 + i;
        if (e < N_EDGES) {
            int d = dst[e];
            int b = d >> 7;
            int pos = bucketStart[b] + perBlockBase[blockIdx.x * NB + b]
                    + atomicAdd(&cur[b], 1);
            binned[pos] = ((unsigned int)src[e] << 7) | (unsigned int)(d & 127);
        }
    }
}

// ---------------------------------------------------------------------------
// bucket_agg: one block per bucket (128 dst nodes). 32KB LDS accumulator.
// Streams the bucket's edges: 64 packed words loaded per lane, shfl-broadcast,
// each edge = coalesced 256B row gather + 64-lane LDS atomic add (2-way banks,
// free). Degree counted with one divergent LDS atomic per 64 edges.
// FUSE2=0: write mean rows. FUSE2=1: fused BN2+ReLU+classifier epilogue.
// ---------------------------------------------------------------------------
template<int FUSE2>
__global__ __launch_bounds__(256) void bucket_agg(
    const float* __restrict__ feat,        // [N,64]
    const unsigned int* __restrict__ binned,
    const int* __restrict__ bucketStart,
    float* __restrict__ meanOut,           // FUSE2=0
    const float* __restrict__ r1,          // FUSE2=1: [N,64]
    const float* __restrict__ b2l,
    const float* __restrict__ g2, const float* __restrict__ be2,
    const float* __restrict__ m2, const float* __restrict__ v2,
    const float* __restrict__ Wc, const float* __restrict__ bc,
    float* __restrict__ out)               // [N,2]
{
    __shared__ float acc[NPB * 64];
    __shared__ int   scnt[NPB];

    const int t    = threadIdx.x;
    const int w    = t >> 6;
    const int lane = t & 63;

    for (int i = t; i < NPB * 64; i += 256) acc[i] = 0.0f;
    if (t < NPB) scnt[t] = 0;
    __syncthreads();

    const int bs = bucketStart[blockIdx.x];
    const int be = bucketStart[blockIdx.x + 1];
    const int total = be - bs;
    const int wlen  = (total + 3) >> 2;
    const int wsrt  = bs + w * wlen;
    const int wend  = min(wsrt + wlen, be);

    for (int base = wsrt; base < wend; base += 64) {
        int n = wend - base;
        if (n >= 64) {
            unsigned int p = binned[base + lane];
            atomicAdd(&scnt[p & 127], 1);
            #pragma unroll 8
            for (int i = 0; i < 64; ++i) {
                unsigned int pi = __shfl(p, i);
                float v = feat[(size_t)(pi >> 7) * 64 + lane];
                atomicAdd(&acc[(pi & 127) * 64 + lane], v);
            }
        } else {
            unsigned int p = 0;
            if (lane < n) {
                p = binned[base + lane];
                atomicAdd(&scnt[p & 127], 1);
            }
            for (int i = 0; i < n; ++i) {
                unsigned int pi = __shfl(p, i);
                float v = feat[(size_t)(pi >> 7) * 64 + lane];
                atomicAdd(&acc[(pi & 127) * 64 + lane], v);
            }
        }
    }
    __syncthreads();

    // ---- epilogue: wave w handles rows w, w+4, ... (column access: 2-way banks)
    const int n0 = blockIdx.x * NPB;
    if (!FUSE2) {
        for (int r = w; r < NPB; r += 4) {
            int node = n0 + r;
            if (node >= N_NODES) break;
            float inv = 1.0f / fmaxf((float)scnt[r], 1.0f);
            meanOut[(size_t)node * 64 + lane] = acc[r * 64 + lane] * inv;
        }
    } else {
        float bl  = b2l[lane];
        float s2  = g2[lane] * rsqrtf(v2[lane] + BN_EPS);
        float mm  = m2[lane], bb = be2[lane];
        float wc0 = Wc[lane * 2 + 0], wc1 = Wc[lane * 2 + 1];
        float bc0 = bc[0], bc1 = bc[1];
        for (int r = w; r < NPB; r += 4) {
            int node = n0 + r;
            if (node >= N_NODES) break;
            float inv = 1.0f / fmaxf((float)scnt[r], 1.0f);
            float pre = acc[r * 64 + lane] * inv + bl
                      + r1[(size_t)node * 64 + lane];
            float h2 = fmaxf((pre - mm) * s2 + bb, 0.0f);
            float l0 = h2 * wc0, l1 = h2 * wc1;
            #pragma unroll
            for (int off = 32; off > 0; off >>= 1) {
                l0 += __shfl_xor(l0, off);
                l1 += __shfl_xor(l1, off);
            }
            if (lane == 0) {
                out[(size_t)node * 2 + 0] = l0 + bc0;
                out[(size_t)node * 2 + 1] = l1 + bc1;
            }
        }
    }
}

// ---------------------------------------------------------------------------
// gemm128: per block, C[128 nodes][128 j] = A1@Wtop + A2@Wbot (+epilogue).
// (unchanged from round 4 — passed, ~45us each)
// ---------------------------------------------------------------------------
template<int EPI>
__global__ __launch_bounds__(256) void gemm128(
    const float* __restrict__ A1, const float* __restrict__ A2, int sA,
    const float* __restrict__ W00, const float* __restrict__ W01,
    const float* __restrict__ W10, const float* __restrict__ W11, int sW,
    float* __restrict__ out0, float* __restrict__ out1, int sOut,
    const float* __restrict__ bias,
    const float* __restrict__ g, const float* __restrict__ be,
    const float* __restrict__ mu, const float* __restrict__ var)
{
    __shared__ float Al[128][128];   // [k][node]
    __shared__ float Wl[128][132];   // [k][j] (+4 pad)

    const int t  = threadIdx.x;
    const int n0 = blockIdx.x * 128;

    // ---- stage A (transpose rows -> [k][n]) ----
    {
        const int q  = t & 3;
        const int rl = t >> 2;
        #pragma unroll
        for (int p = 0; p < 2; ++p) {
            const int r  = rl + 64 * p;
            const int nn = n0 + r;
            if (nn < N_NODES) {
                const float4* p1 = (const float4*)(A1 + (size_t)nn * sA) + q * 4;
                const float4* p2 = (const float4*)(A2 + (size_t)nn * sA) + q * 4;
                #pragma unroll
                for (int i = 0; i < 4; ++i) {
                    float4 v = p1[i];
                    int k = q * 16 + i * 4;
                    Al[k+0][r] = v.x; Al[k+1][r] = v.y;
                    Al[k+2][r] = v.z; Al[k+3][r] = v.w;
                }
                #pragma unroll
                for (int i = 0; i < 4; ++i) {
                    float4 v = p2[i];
                    int k = 64 + q * 16 + i * 4;
                    Al[k+0][r] = v.x; Al[k+1][r] = v.y;
                    Al[k+2][r] = v.z; Al[k+3][r] = v.w;
                }
            } else {
                #pragma unroll
                for (int i = 0; i < 4; ++i) {
                    int k = q * 16 + i * 4;
                    #pragma unroll
                    for (int c = 0; c < 4; ++c) {
                        Al[k+c][r] = 0.f;
                        Al[64+k+c][r] = 0.f;
                    }
                }
            }
        }
    }
    // ---- stage W ----
    {
        const int k   = t >> 1;
        const int h   = t & 1;
        const int klo = k & 63;
        const float* srcp = (k < 64) ? (h ? W01 : W00) : (h ? W11 : W10);
        srcp += (size_t)klo * sW;
        #pragma unroll
        for (int i = 0; i < 16; ++i) {
            float4 v = ((const float4*)srcp)[i];
            *(float4*)&Wl[k][h * 64 + i * 4] = v;
        }
    }
    __syncthreads();

    // ---- compute ----
    const int w  = t >> 6, l = t & 63;
    const int n8 = (w & 1) * 64 + (l & 7) * 8;
    const int j8 = (w >> 1) * 64 + (l >> 3) * 8;

    float acc[8][8] = {};
    #pragma unroll 4
    for (int k = 0; k < 128; ++k) {
        float4 a0 = *(const float4*)&Al[k][n8];
        float4 a1 = *(const float4*)&Al[k][n8 + 4];
        float4 w0 = *(const float4*)&Wl[k][j8];
        float4 w1 = *(const float4*)&Wl[k][j8 + 4];
        float av[8] = {a0.x, a0.y, a0.z, a0.w, a1.x, a1.y, a1.z, a1.w};
        float wv[8] = {w0.x, w0.y, w0.z, w0.w, w1.x, w1.y, w1.z, w1.w};
        #pragma unroll
        for (int r = 0; r < 8; ++r)
            #pragma unroll
            for (int c = 0; c < 8; ++c)
                acc[r][c] = fmaf(av[r], wv[c], acc[r][c]);
    }

    // ---- epilogue + store ----
    const int  jloc = j8 & 63;
    float* const op = (j8 < 64) ? out0 : out1;
    float scale[8], off[8];
    if (EPI) {
        #pragma unroll
        for (int c = 0; c < 8; ++c) {
            int j = j8 + c;
            float s = g[j] * rsqrtf(var[j] + BN_EPS);
            scale[c] = s;
            off[c]   = be[j] + (bias[j] - mu[j]) * s;
        }
    }
    #pragma unroll
    for (int r = 0; r < 8; ++r) {
        int node = n0 + n8 + r;
        if (node < N_NODES) {
            float vals[8];
            #pragma unroll
            for (int c = 0; c < 8; ++c) {
                float v = acc[r][c];
                if (EPI) v = fmaxf(fmaf(v, scale[c], off[c]), 0.0f);
                vals[c] = v;
            }
            float4* dp = (float4*)(op + (size_t)node * sOut + jloc);
            dp[0] = make_float4(vals[0], vals[1], vals[2], vals[3]);
            dp[1] = make_float4(vals[4], vals[5], vals[6], vals[7]);
        }
    }
}

// ---------------------------------------------------------------------------
extern "C" void kernel_launch(void* const* d_in, const int* in_sizes, int n_in,
                              void* d_out, int out_size, void* d_ws, size_t ws_size,
                              hipStream_t stream)
{
    const float* x    = (const float*)d_in[0];
    const int*   eidx = (const int*)d_in[1];   // [2, E]: row 0 = src, row 1 = dst
    const float* W1l  = (const float*)d_in[2];
    const float* b1l  = (const float*)d_in[3];
    const float* W1r  = (const float*)d_in[4];
    const float* W2l  = (const float*)d_in[5];
    const float* b2l  = (const float*)d_in[6];
    const float* W2r  = (const float*)d_in[7];
    const float* g1   = (const float*)d_in[8];
    const float* be1  = (const float*)d_in[9];
    const float* m1   = (const float*)d_in[10];
    const float* v1   = (const float*)d_in[11];
    const float* g2   = (const float*)d_in[12];
    const float* be2  = (const float*)d_in[13];
    const float* m2   = (const float*)d_in[14];
    const float* v2   = (const float*)d_in[15];
    const float* Wc   = (const float*)d_in[16];
    const float* bc   = (const float*)d_in[17];
    float* out = (float*)d_out;

    const int* src = eidx;
    const int* dst = eidx + N_EDGES;

    // ---- workspace layout ----
    char* ws = (char*)d_ws;
    size_t off = 0;
    auto alloc = [&](size_t bytes) { void* p = ws + off; off = (off + bytes + 255) & ~(size_t)255; return p; };
    int* bucketTotal  = (int*)alloc((size_t)NB * 4);
    int* bucketStart  = (int*)alloc((size_t)(NB + 1) * 4);
    int* perBlockBase = (int*)alloc((size_t)BIN_BLOCKS * NB * 4);
    unsigned int* binned = (unsigned int*)alloc((size_t)N_EDGES * 4);
    float* bufA = (float*)alloc((size_t)N_NODES * 64 * 4);   // mean1, then t1
    float* bufB = (float*)alloc((size_t)N_NODES * 64 * 4);   // r1
    float* bufH = (float*)alloc((size_t)N_NODES * 128 * 4);  // h1

    const int gemmGrid = (N_NODES + 127) / 128;              // 782

    // ---- bucketed counting sort of edges by dst ----
    hipMemsetAsync(bucketTotal, 0, (size_t)NB * 4, stream);
    bin_count  <<<BIN_BLOCKS, 256, 0, stream>>>(dst, bucketTotal, perBlockBase);
    bucket_scan<<<1, 1024, 0, stream>>>(bucketTotal, bucketStart);
    bin_write  <<<BIN_BLOCKS, 256, 0, stream>>>(src, dst, bucketStart, perBlockBase, binned);

    // ---- layer 1: mean1 -> bufA ----
    bucket_agg<0><<<NB, 256, 0, stream>>>(x, binned, bucketStart, bufA,
                                          nullptr, nullptr, nullptr, nullptr,
                                          nullptr, nullptr, nullptr, nullptr, nullptr);

    // h1 = relu(bn1(mean@W1l + b1l + x@W1r)) -> bufH
    gemm128<1><<<gemmGrid, 256, 0, stream>>>(
        bufA, x, 64,
        W1l, W1l + 64, W1r, W1r + 64, 128,
        bufH, bufH + 64, 128,
        b1l, g1, be1, m1, v1);

    // t1 = h1@W2l -> bufA ; r1 = h1@W2r -> bufB
    gemm128<0><<<gemmGrid, 256, 0, stream>>>(
        bufH, bufH + 64, 128,
        W2l, W2r, W2l + 64 * 64, W2r + 64 * 64, 64,
        bufA, bufB, 64,
        nullptr, nullptr, nullptr, nullptr, nullptr);

    // ---- layer 2: aggregate t1 + fused BN2/ReLU/classifier -> out ----
    bucket_agg<1><<<NB, 256, 0, stream>>>(bufA, binned, bucketStart, nullptr,
                                          bufB, b2l, g2, be2, m2, v2, Wc, bc, out);
}

// Round 6
// 366.597 us; speedup vs baseline: 4.4525x; 4.4525x over previous
//
#include <hip/hip_runtime.h>
#include <math.h>

#define N_NODES 100000
#define IN_DIM 64
#define HID 128
#define HID2 64
#define N_EDGES 1600000
#define BN_EPS 1e-5f

// bucketing: 128 dst nodes per bucket
#define NPB 128
#define NB 782            // ceil(100000/128)
#define BIN_BLOCKS 391
#define BIN_CHUNK 4096    // 391*4096 >= 1.6M
#define SORT_CAP 4096     // bucket capacity for LDS sort (mean 2048, sigma ~45)

// ---------------------------------------------------------------------------
// Binning pass 1: per-block bucket histogram; reserve per-(block,bucket) space
// ---------------------------------------------------------------------------
__global__ __launch_bounds__(256) void bin_count(
    const int* __restrict__ dst,
    int* __restrict__ bucketTotal,     // [NB] (zeroed)
    int* __restrict__ perBlockBase)    // [BIN_BLOCKS*NB]
{
    __shared__ int cnt[NB];
    const int t = threadIdx.x;
    for (int i = t; i < NB; i += 256) cnt[i] = 0;
    __syncthreads();
    const int e0 = blockIdx.x * BIN_CHUNK;
    for (int i = t; i < BIN_CHUNK; i += 256) {
        int e = e0 + i;
        if (e < N_EDGES) atomicAdd(&cnt[dst[e] >> 7], 1);
    }
    __syncthreads();
    for (int b = t; b < NB; b += 256) {
        int c = cnt[b];
        if (c) perBlockBase[blockIdx.x * NB + b] = atomicAdd(&bucketTotal[b], c);
    }
}

// ---------------------------------------------------------------------------
// Binning pass 2: exclusive scan of the 782 bucket totals (one block)
// ---------------------------------------------------------------------------
__global__ __launch_bounds__(1024) void bucket_scan(
    const int* __restrict__ bucketTotal, int* __restrict__ bucketStart)
{
    __shared__ int s[1024];
    const int t = threadIdx.x;
    int v = (t < NB) ? bucketTotal[t] : 0;
    s[t] = v;
    __syncthreads();
    #pragma unroll
    for (int off = 1; off < 1024; off <<= 1) {
        int u = (t >= off) ? s[t - off] : 0;
        __syncthreads();
        s[t] += u;
        __syncthreads();
    }
    if (t < NB) bucketStart[t] = s[t] - v;
    if (t == 0) bucketStart[NB] = N_EDGES;
}

// ---------------------------------------------------------------------------
// Binning pass 3: write packed (src<<7 | localDst) into bucket-grouped order
// ---------------------------------------------------------------------------
__global__ __launch_bounds__(256) void bin_write(
    const int* __restrict__ src, const int* __restrict__ dst,
    const int* __restrict__ bucketStart,
    const int* __restrict__ perBlockBase,
    unsigned int* __restrict__ binned)   // [E]
{
    __shared__ int cur[NB];
    const int t = threadIdx.x;
    for (int i = t; i < NB; i += 256) cur[i] = 0;
    __syncthreads();
    const int e0 = blockIdx.x * BIN_CHUNK;
    for (int i = t; i < BIN_CHUNK; i += 256) {
        int e = e0 + i;
        if (e < N_EDGES) {
            int d = dst[e];
            int b = d >> 7;
            int pos = bucketStart[b] + perBlockBase[blockIdx.x * NB + b]
                    + atomicAdd(&cur[b], 1);
            binned[pos] = ((unsigned int)src[e] << 7) | (unsigned int)(d & 127);
        }
    }
}

// ---------------------------------------------------------------------------
// bucket_sort: one block per bucket. Stage the bucket's packed edges in LDS,
// 128-bin histogram + exclusive scan, emit rowStart[node], then scatter srcs
// into exact dst order and write sortedSrc as one contiguous run (coalesced,
// no write amplification). Fallback to global-cursor scatter if > SORT_CAP
// (cannot trigger for this distribution: mean 2048, needs +45 sigma).
// ---------------------------------------------------------------------------
__global__ __launch_bounds__(256) void bucket_sort(
    const unsigned int* __restrict__ binned,
    const int* __restrict__ bucketStart,
    int* __restrict__ sortedSrc,      // [E]
    int* __restrict__ rowStart)       // [N+1]
{
    __shared__ unsigned int stage[SORT_CAP];
    __shared__ int hist[NPB];
    __shared__ int cur[NPB];

    const int b  = blockIdx.x;
    const int t  = threadIdx.x;
    const int bs = bucketStart[b];
    const int be = bucketStart[b + 1];
    const int total = be - bs;

    if (t < NPB) hist[t] = 0;
    __syncthreads();

    if (total <= SORT_CAP) {
        // load + histogram
        for (int i = t; i < total; i += 256) {
            unsigned int p = binned[bs + i];
            stage[i] = p;
            atomicAdd(&hist[p & 127], 1);
        }
        __syncthreads();
        int orig = (t < NPB) ? hist[t] : 0;
        __syncthreads();
        // Hillis-Steele inclusive scan over 128 bins
        #pragma unroll
        for (int off = 1; off < NPB; off <<= 1) {
            int v = (t < NPB && t >= off) ? hist[t - off] : 0;
            __syncthreads();
            if (t < NPB) hist[t] += v;
            __syncthreads();
        }
        if (t < NPB) {
            int excl = hist[t] - orig;
            int node = b * NPB + t;
            if (node < N_NODES) rowStart[node] = bs + excl;
            cur[t] = excl;
        }
        if (b == 0 && t == 0) rowStart[N_NODES] = N_EDGES;
        __syncthreads();
        // scatter into exact order; writes land in one contiguous run
        for (int i = t; i < total; i += 256) {
            unsigned int p = stage[i];
            int pos = atomicAdd(&cur[p & 127], 1);
            sortedSrc[bs + pos] = (int)(p >> 7);
        }
    } else {
        // fallback (never expected): histogram from global, then global scatter
        for (int i = t; i < total; i += 256)
            atomicAdd(&hist[binned[bs + i] & 127], 1);
        __syncthreads();
        int orig = (t < NPB) ? hist[t] : 0;
        __syncthreads();
        #pragma unroll
        for (int off = 1; off < NPB; off <<= 1) {
            int v = (t < NPB && t >= off) ? hist[t - off] : 0;
            __syncthreads();
            if (t < NPB) hist[t] += v;
            __syncthreads();
        }
        if (t < NPB) {
            int excl = hist[t] - orig;
            int node = b * NPB + t;
            if (node < N_NODES) rowStart[node] = bs + excl;
            cur[t] = excl;
        }
        if (b == 0 && t == 0) rowStart[N_NODES] = N_EDGES;
        __syncthreads();
        for (int i = t; i < total; i += 256) {
            unsigned int p = binned[bs + i];
            int pos = atomicAdd(&cur[p & 127], 1);
            sortedSrc[bs + pos] = (int)(p >> 7);
        }
    }
}

// ---------------------------------------------------------------------------
// Aggregation by gather: one wave per node, lane = feature (64-wide rows).
// 8 independent accumulators -> 8 row-loads in flight per wave.
// ---------------------------------------------------------------------------
__global__ __launch_bounds__(256) void gather_mean(
    const float* __restrict__ feat,      // [N,64]
    const int* __restrict__ rowStart,    // [N+1]
    const int* __restrict__ sortedSrc,   // [E]
    float* __restrict__ mean)            // [N,64]
{
    int node = (int)((blockIdx.x * 256u + threadIdx.x) >> 6);
    int lane = threadIdx.x & 63;
    if (node >= N_NODES) return;
    int b = rowStart[node];
    int e = rowStart[node + 1];
    float a0 = 0.f, a1 = 0.f, a2 = 0.f, a3 = 0.f;
    float a4 = 0.f, a5 = 0.f, a6 = 0.f, a7 = 0.f;
    int j = b;
    for (; j + 8 <= e; j += 8) {
        int s0 = sortedSrc[j + 0];
        int s1 = sortedSrc[j + 1];
        int s2 = sortedSrc[j + 2];
        int s3 = sortedSrc[j + 3];
        int s4 = sortedSrc[j + 4];
        int s5 = sortedSrc[j + 5];
        int s6 = sortedSrc[j + 6];
        int s7 = sortedSrc[j + 7];
        a0 += feat[(size_t)s0 * 64 + lane];
        a1 += feat[(size_t)s1 * 64 + lane];
        a2 += feat[(size_t)s2 * 64 + lane];
        a3 += feat[(size_t)s3 * 64 + lane];
        a4 += feat[(size_t)s4 * 64 + lane];
        a5 += feat[(size_t)s5 * 64 + lane];
        a6 += feat[(size_t)s6 * 64 + lane];
        a7 += feat[(size_t)s7 * 64 + lane];
    }
    for (; j < e; ++j) a0 += feat[(size_t)sortedSrc[j] * 64 + lane];
    float sum = ((a0 + a1) + (a2 + a3)) + ((a4 + a5) + (a6 + a7));
    float inv = 1.0f / fmaxf((float)(e - b), 1.0f);
    mean[(size_t)node * 64 + lane] = sum * inv;
}

// ---------------------------------------------------------------------------
// gemm128: per block, C[128 nodes][128 j] = A1@Wtop + A2@Wbot (+epilogue).
// ---------------------------------------------------------------------------
template<int EPI>
__global__ __launch_bounds__(256) void gemm128(
    const float* __restrict__ A1, const float* __restrict__ A2, int sA,
    const float* __restrict__ W00, const float* __restrict__ W01,
    const float* __restrict__ W10, const float* __restrict__ W11, int sW,
    float* __restrict__ out0, float* __restrict__ out1, int sOut,
    const float* __restrict__ bias,
    const float* __restrict__ g, const float* __restrict__ be,
    const float* __restrict__ mu, const float* __restrict__ var)
{
    __shared__ float Al[128][128];   // [k][node]
    __shared__ float Wl[128][132];   // [k][j] (+4 pad)

    const int t  = threadIdx.x;
    const int n0 = blockIdx.x * 128;

    // ---- stage A (transpose rows -> [k][n]) ----
    {
        const int q  = t & 3;
        const int rl = t >> 2;
        #pragma unroll
        for (int p = 0; p < 2; ++p) {
            const int r  = rl + 64 * p;
            const int nn = n0 + r;
            if (nn < N_NODES) {
                const float4* p1 = (const float4*)(A1 + (size_t)nn * sA) + q * 4;
                const float4* p2 = (const float4*)(A2 + (size_t)nn * sA) + q * 4;
                #pragma unroll
                for (int i = 0; i < 4; ++i) {
                    float4 v = p1[i];
                    int k = q * 16 + i * 4;
                    Al[k+0][r] = v.x; Al[k+1][r] = v.y;
                    Al[k+2][r] = v.z; Al[k+3][r] = v.w;
                }
                #pragma unroll
                for (int i = 0; i < 4; ++i) {
                    float4 v = p2[i];
                    int k = 64 + q * 16 + i * 4;
                    Al[k+0][r] = v.x; Al[k+1][r] = v.y;
                    Al[k+2][r] = v.z; Al[k+3][r] = v.w;
                }
            } else {
                #pragma unroll
                for (int i = 0; i < 4; ++i) {
                    int k = q * 16 + i * 4;
                    #pragma unroll
                    for (int c = 0; c < 4; ++c) {
                        Al[k+c][r] = 0.f;
                        Al[64+k+c][r] = 0.f;
                    }
                }
            }
        }
    }
    // ---- stage W ----
    {
        const int k   = t >> 1;
        const int h   = t & 1;
        const int klo = k & 63;
        const float* srcp = (k < 64) ? (h ? W01 : W00) : (h ? W11 : W10);
        srcp += (size_t)klo * sW;
        #pragma unroll
        for (int i = 0; i < 16; ++i) {
            float4 v = ((const float4*)srcp)[i];
            *(float4*)&Wl[k][h * 64 + i * 4] = v;
        }
    }
    __syncthreads();

    // ---- compute ----
    const int w  = t >> 6, l = t & 63;
    const int n8 = (w & 1) * 64 + (l & 7) * 8;
    const int j8 = (w >> 1) * 64 + (l >> 3) * 8;

    float acc[8][8] = {};
    #pragma unroll 4
    for (int k = 0; k < 128; ++k) {
        float4 a0 = *(const float4*)&Al[k][n8];
        float4 a1 = *(const float4*)&Al[k][n8 + 4];
        float4 w0 = *(const float4*)&Wl[k][j8];
        float4 w1 = *(const float4*)&Wl[k][j8 + 4];
        float av[8] = {a0.x, a0.y, a0.z, a0.w, a1.x, a1.y, a1.z, a1.w};
        float wv[8] = {w0.x, w0.y, w0.z, w0.w, w1.x, w1.y, w1.z, w1.w};
        #pragma unroll
        for (int r = 0; r < 8; ++r)
            #pragma unroll
            for (int c = 0; c < 8; ++c)
                acc[r][c] = fmaf(av[r], wv[c], acc[r][c]);
    }

    // ---- epilogue + store ----
    const int  jloc = j8 & 63;
    float* const op = (j8 < 64) ? out0 : out1;
    float scale[8], off[8];
    if (EPI) {
        #pragma unroll
        for (int c = 0; c < 8; ++c) {
            int j = j8 + c;
            float s = g[j] * rsqrtf(var[j] + BN_EPS);
            scale[c] = s;
            off[c]   = be[j] + (bias[j] - mu[j]) * s;
        }
    }
    #pragma unroll
    for (int r = 0; r < 8; ++r) {
        int node = n0 + n8 + r;
        if (node < N_NODES) {
            float vals[8];
            #pragma unroll
            for (int c = 0; c < 8; ++c) {
                float v = acc[r][c];
                if (EPI) v = fmaxf(fmaf(v, scale[c], off[c]), 0.0f);
                vals[c] = v;
            }
            float4* dp = (float4*)(op + (size_t)node * sOut + jloc);
            dp[0] = make_float4(vals[0], vals[1], vals[2], vals[3]);
            dp[1] = make_float4(vals[4], vals[5], vals[6], vals[7]);
        }
    }
}

// ---------------------------------------------------------------------------
// node2: one wave per node; elementwise BN/ReLU + 2-logit reduce.
// ---------------------------------------------------------------------------
__global__ __launch_bounds__(256) void node2_kernel(
    const float* __restrict__ mean2,  // [N,64]
    const float* __restrict__ r1,     // [N,64]
    const float* __restrict__ b2l,    // [64]
    const float* __restrict__ g2, const float* __restrict__ be2,
    const float* __restrict__ m2, const float* __restrict__ v2,
    const float* __restrict__ Wc,     // [64,2]
    const float* __restrict__ bc,     // [2]
    float* __restrict__ out)          // [N,2]
{
    int node = (int)((blockIdx.x * 256u + threadIdx.x) >> 6);
    int lane = threadIdx.x & 63;
    if (node >= N_NODES) return;

    float pre = mean2[(size_t)node * 64 + lane] + b2l[lane]
              + r1[(size_t)node * 64 + lane];
    float s  = g2[lane] * rsqrtf(v2[lane] + BN_EPS);
    float h2 = fmaxf((pre - m2[lane]) * s + be2[lane], 0.0f);

    float l0 = h2 * Wc[lane * 2 + 0];
    float l1 = h2 * Wc[lane * 2 + 1];
    #pragma unroll
    for (int off = 32; off > 0; off >>= 1) {
        l0 += __shfl_xor(l0, off);
        l1 += __shfl_xor(l1, off);
    }
    if (lane == 0) {
        out[(size_t)node * 2 + 0] = l0 + bc[0];
        out[(size_t)node * 2 + 1] = l1 + bc[1];
    }
}

// ---------------------------------------------------------------------------
extern "C" void kernel_launch(void* const* d_in, const int* in_sizes, int n_in,
                              void* d_out, int out_size, void* d_ws, size_t ws_size,
                              hipStream_t stream)
{
    const float* x    = (const float*)d_in[0];
    const int*   eidx = (const int*)d_in[1];   // [2, E]: row 0 = src, row 1 = dst
    const float* W1l  = (const float*)d_in[2];
    const float* b1l  = (const float*)d_in[3];
    const float* W1r  = (const float*)d_in[4];
    const float* W2l  = (const float*)d_in[5];
    const float* b2l  = (const float*)d_in[6];
    const float* W2r  = (const float*)d_in[7];
    const float* g1   = (const float*)d_in[8];
    const float* be1  = (const float*)d_in[9];
    const float* m1   = (const float*)d_in[10];
    const float* v1   = (const float*)d_in[11];
    const float* g2   = (const float*)d_in[12];
    const float* be2  = (const float*)d_in[13];
    const float* m2   = (const float*)d_in[14];
    const float* v2   = (const float*)d_in[15];
    const float* Wc   = (const float*)d_in[16];
    const float* bc   = (const float*)d_in[17];
    float* out = (float*)d_out;

    const int* src = eidx;
    const int* dst = eidx + N_EDGES;

    // ---- workspace layout ----
    char* ws = (char*)d_ws;
    size_t off = 0;
    auto alloc = [&](size_t bytes) { void* p = ws + off; off = (off + bytes + 255) & ~(size_t)255; return p; };
    int* bucketTotal  = (int*)alloc((size_t)NB * 4);
    int* bucketStart  = (int*)alloc((size_t)(NB + 1) * 4);
    int* perBlockBase = (int*)alloc((size_t)BIN_BLOCKS * NB * 4);
    unsigned int* binned = (unsigned int*)alloc((size_t)N_EDGES * 4);
    int* sortedSrc    = (int*)alloc((size_t)N_EDGES * 4);
    int* rowStart     = (int*)alloc((size_t)(N_NODES + 1) * 4);
    float* bufA = (float*)alloc((size_t)N_NODES * 64 * 4);   // mean1, then t1
    float* bufB = (float*)alloc((size_t)N_NODES * 64 * 4);   // r1
    float* bufH = (float*)alloc((size_t)N_NODES * 128 * 4);  // h1, then mean2

    const int gemmGrid     = (N_NODES + 127) / 128;          // 782
    const int nodeWaveGrid = (N_NODES * 64 + 255) / 256;     // 25000

    // ---- counting sort of edges by dst (bucket pass + per-bucket LDS sort) ----
    hipMemsetAsync(bucketTotal, 0, (size_t)NB * 4, stream);
    bin_count  <<<BIN_BLOCKS, 256, 0, stream>>>(dst, bucketTotal, perBlockBase);
    bucket_scan<<<1, 1024, 0, stream>>>(bucketTotal, bucketStart);
    bin_write  <<<BIN_BLOCKS, 256, 0, stream>>>(src, dst, bucketStart, perBlockBase, binned);
    bucket_sort<<<NB, 256, 0, stream>>>(binned, bucketStart, sortedSrc, rowStart);

    // ---- layer 1 ----
    gather_mean<<<nodeWaveGrid, 256, 0, stream>>>(x, rowStart, sortedSrc, bufA);

    // h1 = relu(bn1(mean@W1l + b1l + x@W1r)) -> bufH
    gemm128<1><<<gemmGrid, 256, 0, stream>>>(
        bufA, x, 64,
        W1l, W1l + 64, W1r, W1r + 64, 128,
        bufH, bufH + 64, 128,
        b1l, g1, be1, m1, v1);

    // t1 = h1@W2l -> bufA ; r1 = h1@W2r -> bufB
    gemm128<0><<<gemmGrid, 256, 0, stream>>>(
        bufH, bufH + 64, 128,
        W2l, W2r, W2l + 64 * 64, W2r + 64 * 64, 64,
        bufA, bufB, 64,
        nullptr, nullptr, nullptr, nullptr, nullptr);

    // ---- layer 2: mean of t1 -> bufH (h1 dead) ----
    gather_mean<<<nodeWaveGrid, 256, 0, stream>>>(bufA, rowStart, sortedSrc, bufH);

    node2_kernel<<<nodeWaveGrid, 256, 0, stream>>>(bufH, bufB, b2l,
                                                   g2, be2, m2, v2, Wc, bc, out);
}

// Round 7
// 302.253 us; speedup vs baseline: 5.4003x; 1.2129x over previous
//
#include <hip/hip_runtime.h>
#include <math.h>

#define N_NODES 100000
#define IN_DIM 64
#define HID 128
#define HID2 64
#define N_EDGES 1600000
#define BN_EPS 1e-5f

// bucketing: 128 dst nodes per bucket
#define NPB 128
#define NB 782            // ceil(100000/128)
#define BIN_BLOCKS 391
#define BIN_CHUNK 4096    // 391*4096 >= 1.6M
#define SORT_CAP 4096     // bucket capacity for LDS sort (mean 2048, sigma ~45)

// ---------------------------------------------------------------------------
// Binning pass 1: per-block bucket histogram; reserve per-(block,bucket) space
// ---------------------------------------------------------------------------
__global__ __launch_bounds__(256) void bin_count(
    const int* __restrict__ dst,
    int* __restrict__ bucketTotal,     // [NB] (zeroed)
    int* __restrict__ perBlockBase)    // [BIN_BLOCKS*NB]
{
    __shared__ int cnt[NB];
    const int t = threadIdx.x;
    for (int i = t; i < NB; i += 256) cnt[i] = 0;
    __syncthreads();
    const int e0 = blockIdx.x * BIN_CHUNK;
    for (int i = t; i < BIN_CHUNK; i += 256) {
        int e = e0 + i;
        if (e < N_EDGES) atomicAdd(&cnt[dst[e] >> 7], 1);
    }
    __syncthreads();
    for (int b = t; b < NB; b += 256) {
        int c = cnt[b];
        if (c) perBlockBase[blockIdx.x * NB + b] = atomicAdd(&bucketTotal[b], c);
    }
}

// ---------------------------------------------------------------------------
// Binning pass 2: exclusive scan of the 782 bucket totals (one block)
// ---------------------------------------------------------------------------
__global__ __launch_bounds__(1024) void bucket_scan(
    const int* __restrict__ bucketTotal, int* __restrict__ bucketStart)
{
    __shared__ int s[1024];
    const int t = threadIdx.x;
    int v = (t < NB) ? bucketTotal[t] : 0;
    s[t] = v;
    __syncthreads();
    #pragma unroll
    for (int off = 1; off < 1024; off <<= 1) {
        int u = (t >= off) ? s[t - off] : 0;
        __syncthreads();
        s[t] += u;
        __syncthreads();
    }
    if (t < NB) bucketStart[t] = s[t] - v;
    if (t == 0) bucketStart[NB] = N_EDGES;
}

// ---------------------------------------------------------------------------
// Binning pass 3: write packed (src<<7 | localDst) into bucket-grouped order
// ---------------------------------------------------------------------------
__global__ __launch_bounds__(256) void bin_write(
    const int* __restrict__ src, const int* __restrict__ dst,
    const int* __restrict__ bucketStart,
    const int* __restrict__ perBlockBase,
    unsigned int* __restrict__ binned)   // [E]
{
    __shared__ int cur[NB];
    const int t = threadIdx.x;
    for (int i = t; i < NB; i += 256) cur[i] = 0;
    __syncthreads();
    const int e0 = blockIdx.x * BIN_CHUNK;
    for (int i = t; i < BIN_CHUNK; i += 256) {
        int e = e0 + i;
        if (e < N_EDGES) {
            int d = dst[e];
            int b = d >> 7;
            int pos = bucketStart[b] + perBlockBase[blockIdx.x * NB + b]
                    + atomicAdd(&cur[b], 1);
            binned[pos] = ((unsigned int)src[e] << 7) | (unsigned int)(d & 127);
        }
    }
}

// ---------------------------------------------------------------------------
// bucket_sort: one block per bucket. Stage packed edges in LDS, 128-bin
// histogram + scan -> rowStart, then local scatter -> sortedSrc (contiguous
// coalesced run per block; no write amplification).
// ---------------------------------------------------------------------------
__global__ __launch_bounds__(256) void bucket_sort(
    const unsigned int* __restrict__ binned,
    const int* __restrict__ bucketStart,
    int* __restrict__ sortedSrc,      // [E]
    int* __restrict__ rowStart)       // [N+1]
{
    __shared__ unsigned int stage[SORT_CAP];
    __shared__ int hist[NPB];
    __shared__ int cur[NPB];

    const int b  = blockIdx.x;
    const int t  = threadIdx.x;
    const int bs = bucketStart[b];
    const int be = bucketStart[b + 1];
    const int total = be - bs;

    if (t < NPB) hist[t] = 0;
    __syncthreads();

    if (total <= SORT_CAP) {
        for (int i = t; i < total; i += 256) {
            unsigned int p = binned[bs + i];
            stage[i] = p;
            atomicAdd(&hist[p & 127], 1);
        }
        __syncthreads();
        int orig = (t < NPB) ? hist[t] : 0;
        __syncthreads();
        #pragma unroll
        for (int off = 1; off < NPB; off <<= 1) {
            int v = (t < NPB && t >= off) ? hist[t - off] : 0;
            __syncthreads();
            if (t < NPB) hist[t] += v;
            __syncthreads();
        }
        if (t < NPB) {
            int excl = hist[t] - orig;
            int node = b * NPB + t;
            if (node < N_NODES) rowStart[node] = bs + excl;
            cur[t] = excl;
        }
        if (b == 0 && t == 0) rowStart[N_NODES] = N_EDGES;
        __syncthreads();
        for (int i = t; i < total; i += 256) {
            unsigned int p = stage[i];
            int pos = atomicAdd(&cur[p & 127], 1);
            sortedSrc[bs + pos] = (int)(p >> 7);
        }
    } else {
        for (int i = t; i < total; i += 256)
            atomicAdd(&hist[binned[bs + i] & 127], 1);
        __syncthreads();
        int orig = (t < NPB) ? hist[t] : 0;
        __syncthreads();
        #pragma unroll
        for (int off = 1; off < NPB; off <<= 1) {
            int v = (t < NPB && t >= off) ? hist[t - off] : 0;
            __syncthreads();
            if (t < NPB) hist[t] += v;
            __syncthreads();
        }
        if (t < NPB) {
            int excl = hist[t] - orig;
            int node = b * NPB + t;
            if (node < N_NODES) rowStart[node] = bs + excl;
            cur[t] = excl;
        }
        if (b == 0 && t == 0) rowStart[N_NODES] = N_EDGES;
        __syncthreads();
        for (int i = t; i < total; i += 256) {
            unsigned int p = binned[bs + i];
            int pos = atomicAdd(&cur[p & 127], 1);
            sortedSrc[bs + pos] = (int)(p >> 7);
        }
    }
}

// ---------------------------------------------------------------------------
// gather_mean: one wave per node, lane = feature. 8 independent accumulators.
// FUSE2=0: write mean rows. FUSE2=1: fused + b2l + r1, BN2, ReLU, classifier.
// ---------------------------------------------------------------------------
template<int FUSE2>
__global__ __launch_bounds__(256) void gather_mean(
    const float* __restrict__ feat,      // [N,64]
    const int* __restrict__ rowStart,    // [N+1]
    const int* __restrict__ sortedSrc,   // [E]
    float* __restrict__ meanOut,         // FUSE2=0
    const float* __restrict__ r1,        // FUSE2=1
    const float* __restrict__ b2l,
    const float* __restrict__ g2, const float* __restrict__ be2,
    const float* __restrict__ m2, const float* __restrict__ v2,
    const float* __restrict__ Wc, const float* __restrict__ bc,
    float* __restrict__ out)             // [N,2]
{
    int node = (int)((blockIdx.x * 256u + threadIdx.x) >> 6);
    int lane = threadIdx.x & 63;
    if (node >= N_NODES) return;
    int b = rowStart[node];
    int e = rowStart[node + 1];
    float a0 = 0.f, a1 = 0.f, a2 = 0.f, a3 = 0.f;
    float a4 = 0.f, a5 = 0.f, a6 = 0.f, a7 = 0.f;
    int j = b;
    for (; j + 8 <= e; j += 8) {
        int s0 = sortedSrc[j + 0];
        int s1 = sortedSrc[j + 1];
        int s2 = sortedSrc[j + 2];
        int s3 = sortedSrc[j + 3];
        int s4 = sortedSrc[j + 4];
        int s5 = sortedSrc[j + 5];
        int s6 = sortedSrc[j + 6];
        int s7 = sortedSrc[j + 7];
        a0 += feat[(size_t)s0 * 64 + lane];
        a1 += feat[(size_t)s1 * 64 + lane];
        a2 += feat[(size_t)s2 * 64 + lane];
        a3 += feat[(size_t)s3 * 64 + lane];
        a4 += feat[(size_t)s4 * 64 + lane];
        a5 += feat[(size_t)s5 * 64 + lane];
        a6 += feat[(size_t)s6 * 64 + lane];
        a7 += feat[(size_t)s7 * 64 + lane];
    }
    for (; j < e; ++j) a0 += feat[(size_t)sortedSrc[j] * 64 + lane];
    float sum = ((a0 + a1) + (a2 + a3)) + ((a4 + a5) + (a6 + a7));
    float inv = 1.0f / fmaxf((float)(e - b), 1.0f);
    float mv  = sum * inv;

    if (!FUSE2) {
        meanOut[(size_t)node * 64 + lane] = mv;
    } else {
        float pre = mv + b2l[lane] + r1[(size_t)node * 64 + lane];
        float s   = g2[lane] * rsqrtf(v2[lane] + BN_EPS);
        float h2  = fmaxf((pre - m2[lane]) * s + be2[lane], 0.0f);
        float l0 = h2 * Wc[lane * 2 + 0];
        float l1 = h2 * Wc[lane * 2 + 1];
        #pragma unroll
        for (int off = 32; off > 0; off >>= 1) {
            l0 += __shfl_xor(l0, off);
            l1 += __shfl_xor(l1, off);
        }
        if (lane == 0) {
            out[(size_t)node * 2 + 0] = l0 + bc[0];
            out[(size_t)node * 2 + 1] = l1 + bc[1];
        }
    }
}

// ---------------------------------------------------------------------------
// gemm_fused: per block of 64 nodes, both layers' dense math in one kernel.
//   phase 1: h1 = relu(bn1(mean@W1l + b1l + x@W1r))   (acc -> LDS, transposed)
//   phase 2: t1 = h1@W2l, r1 = h1@W2r
// LDS: Al[128][65] fp32 = 33.3 KB -> 4 blocks/CU, 4 waves/SIMD.
// W read per-iter from global (64 KB, L2-resident): coalesced float4/lane.
// Wave w: phase-1 output cols [32w,32w+32); phase-2: w<2 -> t1, else r1.
// Lane: 8 nodes x 4 cols microtile.
// ---------------------------------------------------------------------------
__global__ __launch_bounds__(256, 4) void gemm_fused(
    const float* __restrict__ mean,   // [N,64]
    const float* __restrict__ x,      // [N,64]
    const float* __restrict__ W1l,    // [64,128]
    const float* __restrict__ b1l,    // [128]
    const float* __restrict__ W1r,    // [64,128]
    const float* __restrict__ g1, const float* __restrict__ be1,
    const float* __restrict__ m1, const float* __restrict__ v1,
    const float* __restrict__ W2l,    // [128,64]
    const float* __restrict__ W2r,    // [128,64]
    float* __restrict__ t1,           // [N,64]
    float* __restrict__ r1)           // [N,64]
{
    __shared__ float Al[128 * 65];    // [k][n], pad 65 rotates banks per row

    const int t  = threadIdx.x;
    const int n0 = blockIdx.x * 64;

    // ---- stage: Al[0..63][n] = mean^T, Al[64..127][n] = x^T ----
    {
        const int q  = t & 3;         // 16-float chunk of the row
        const int rl = t >> 2;        // node 0..63
        const int nn = n0 + rl;
        if (nn < N_NODES) {
            const float4* pm = (const float4*)(mean + (size_t)nn * 64) + q * 4;
            const float4* px = (const float4*)(x    + (size_t)nn * 64) + q * 4;
            #pragma unroll
            for (int i = 0; i < 4; ++i) {
                float4 v = pm[i];
                int k = q * 16 + i * 4;
                Al[(k+0)*65 + rl] = v.x; Al[(k+1)*65 + rl] = v.y;
                Al[(k+2)*65 + rl] = v.z; Al[(k+3)*65 + rl] = v.w;
            }
            #pragma unroll
            for (int i = 0; i < 4; ++i) {
                float4 v = px[i];
                int k = 64 + q * 16 + i * 4;
                Al[(k+0)*65 + rl] = v.x; Al[(k+1)*65 + rl] = v.y;
                Al[(k+2)*65 + rl] = v.z; Al[(k+3)*65 + rl] = v.w;
            }
        } else {
            #pragma unroll
            for (int i = 0; i < 16; ++i) {
                Al[(q*16 + i)*65 + rl]      = 0.0f;
                Al[(64 + q*16 + i)*65 + rl] = 0.0f;
            }
        }
    }
    __syncthreads();

    const int w  = t >> 6, l = t & 63;
    const int n8 = (l & 7) * 8;               // node base within tile
    const int j8 = w * 32 + (l >> 3) * 4;     // phase-1 output col base

    // ---- phase 1: acc[node][j] over K=128 (mean then x half) ----
    float acc[8][4] = {};
    #pragma unroll 4
    for (int k = 0; k < 64; ++k) {
        float4 a0 = *(const float4*)&Al[k*65 + n8];
        float4 a1 = *(const float4*)&Al[k*65 + n8 + 4];
        float4 wv = *(const float4*)(W1l + k * HID + j8);
        float av[8] = {a0.x,a0.y,a0.z,a0.w,a1.x,a1.y,a1.z,a1.w};
        float wl[4] = {wv.x,wv.y,wv.z,wv.w};
        #pragma unroll
        for (int r = 0; r < 8; ++r)
            #pragma unroll
            for (int c = 0; c < 4; ++c)
                acc[r][c] = fmaf(av[r], wl[c], acc[r][c]);
    }
    #pragma unroll 4
    for (int k = 0; k < 64; ++k) {
        float4 a0 = *(const float4*)&Al[(64+k)*65 + n8];
        float4 a1 = *(const float4*)&Al[(64+k)*65 + n8 + 4];
        float4 wv = *(const float4*)(W1r + k * HID + j8);
        float av[8] = {a0.x,a0.y,a0.z,a0.w,a1.x,a1.y,a1.z,a1.w};
        float wl[4] = {wv.x,wv.y,wv.z,wv.w};
        #pragma unroll
        for (int r = 0; r < 8; ++r)
            #pragma unroll
            for (int c = 0; c < 4; ++c)
                acc[r][c] = fmaf(av[r], wl[c], acc[r][c]);
    }
    __syncthreads();   // everyone done reading phase-1 Al

    // ---- epilogue 1: h1 = relu(bn1(acc)) -> Al[j][n] (transposed) ----
    {
        #pragma unroll
        for (int c = 0; c < 4; ++c) {
            int j = j8 + c;
            float s   = g1[j] * rsqrtf(v1[j] + BN_EPS);
            float off = be1[j] + (b1l[j] - m1[j]) * s;
            float h0 = fmaxf(fmaf(acc[0][c], s, off), 0.0f);
            float h1v = fmaxf(fmaf(acc[1][c], s, off), 0.0f);
            float h2 = fmaxf(fmaf(acc[2][c], s, off), 0.0f);
            float h3 = fmaxf(fmaf(acc[3][c], s, off), 0.0f);
            float h4 = fmaxf(fmaf(acc[4][c], s, off), 0.0f);
            float h5 = fmaxf(fmaf(acc[5][c], s, off), 0.0f);
            float h6 = fmaxf(fmaf(acc[6][c], s, off), 0.0f);
            float h7 = fmaxf(fmaf(acc[7][c], s, off), 0.0f);
            *(float4*)&Al[j*65 + n8]     = make_float4(h0, h1v, h2, h3);
            *(float4*)&Al[j*65 + n8 + 4] = make_float4(h4, h5, h6, h7);
        }
    }
    __syncthreads();

    // ---- phase 2: t1/r1 = h1 @ W2l/W2r over K=128 ----
    const float* W2 = (w < 2) ? W2l : W2r;
    const int    jl = (w & 1) * 32 + (l >> 3) * 4;
    float acc2[8][4] = {};
    #pragma unroll 4
    for (int k = 0; k < 128; ++k) {
        float4 a0 = *(const float4*)&Al[k*65 + n8];
        float4 a1 = *(const float4*)&Al[k*65 + n8 + 4];
        float4 wv = *(const float4*)(W2 + k * HID2 + jl);
        float av[8] = {a0.x,a0.y,a0.z,a0.w,a1.x,a1.y,a1.z,a1.w};
        float wl[4] = {wv.x,wv.y,wv.z,wv.w};
        #pragma unroll
        for (int r = 0; r < 8; ++r)
            #pragma unroll
            for (int c = 0; c < 4; ++c)
                acc2[r][c] = fmaf(av[r], wl[c], acc2[r][c]);
    }

    // ---- epilogue 2: write t1 (w<2) / r1 (w>=2) ----
    float* const op = (w < 2) ? t1 : r1;
    #pragma unroll
    for (int r = 0; r < 8; ++r) {
        int node = n0 + n8 + r;
        if (node < N_NODES)
            *(float4*)(op + (size_t)node * 64 + jl) =
                make_float4(acc2[r][0], acc2[r][1], acc2[r][2], acc2[r][3]);
    }
}

// ---------------------------------------------------------------------------
extern "C" void kernel_launch(void* const* d_in, const int* in_sizes, int n_in,
                              void* d_out, int out_size, void* d_ws, size_t ws_size,
                              hipStream_t stream)
{
    const float* x    = (const float*)d_in[0];
    const int*   eidx = (const int*)d_in[1];   // [2, E]: row 0 = src, row 1 = dst
    const float* W1l  = (const float*)d_in[2];
    const float* b1l  = (const float*)d_in[3];
    const float* W1r  = (const float*)d_in[4];
    const float* W2l  = (const float*)d_in[5];
    const float* b2l  = (const float*)d_in[6];
    const float* W2r  = (const float*)d_in[7];
    const float* g1   = (const float*)d_in[8];
    const float* be1  = (const float*)d_in[9];
    const float* m1   = (const float*)d_in[10];
    const float* v1   = (const float*)d_in[11];
    const float* g2   = (const float*)d_in[12];
    const float* be2  = (const float*)d_in[13];
    const float* m2   = (const float*)d_in[14];
    const float* v2   = (const float*)d_in[15];
    const float* Wc   = (const float*)d_in[16];
    const float* bc   = (const float*)d_in[17];
    float* out = (float*)d_out;

    const int* src = eidx;
    const int* dst = eidx + N_EDGES;

    // ---- workspace layout ----
    char* ws = (char*)d_ws;
    size_t off = 0;
    auto alloc = [&](size_t bytes) { void* p = ws + off; off = (off + bytes + 255) & ~(size_t)255; return p; };
    int* bucketTotal  = (int*)alloc((size_t)NB * 4);
    int* bucketStart  = (int*)alloc((size_t)(NB + 1) * 4);
    int* perBlockBase = (int*)alloc((size_t)BIN_BLOCKS * NB * 4);
    unsigned int* binned = (unsigned int*)alloc((size_t)N_EDGES * 4);
    int* sortedSrc    = (int*)alloc((size_t)N_EDGES * 4);
    int* rowStart     = (int*)alloc((size_t)(N_NODES + 1) * 4);
    float* bufMean = (float*)alloc((size_t)N_NODES * 64 * 4);
    float* t1      = (float*)alloc((size_t)N_NODES * 64 * 4);
    float* r1      = (float*)alloc((size_t)N_NODES * 64 * 4);

    const int gemmGrid     = (N_NODES + 63) / 64;            // 1563
    const int nodeWaveGrid = (N_NODES * 64 + 255) / 256;     // 25000

    // ---- counting sort of edges by dst ----
    hipMemsetAsync(bucketTotal, 0, (size_t)NB * 4, stream);
    bin_count  <<<BIN_BLOCKS, 256, 0, stream>>>(dst, bucketTotal, perBlockBase);
    bucket_scan<<<1, 1024, 0, stream>>>(bucketTotal, bucketStart);
    bin_write  <<<BIN_BLOCKS, 256, 0, stream>>>(src, dst, bucketStart, perBlockBase, binned);
    bucket_sort<<<NB, 256, 0, stream>>>(binned, bucketStart, sortedSrc, rowStart);

    // ---- layer 1: mean -> bufMean ----
    gather_mean<0><<<nodeWaveGrid, 256, 0, stream>>>(
        x, rowStart, sortedSrc, bufMean,
        nullptr, nullptr, nullptr, nullptr, nullptr, nullptr, nullptr, nullptr, nullptr);

    // ---- fused dense: h1 (internal) -> t1, r1 ----
    gemm_fused<<<gemmGrid, 256, 0, stream>>>(
        bufMean, x, W1l, b1l, W1r, g1, be1, m1, v1, W2l, W2r, t1, r1);

    // ---- layer 2: gather t1 + fused BN2/ReLU/classifier -> out ----
    gather_mean<1><<<nodeWaveGrid, 256, 0, stream>>>(
        t1, rowStart, sortedSrc, nullptr,
        r1, b2l, g2, be2, m2, v2, Wc, bc, out);
}

// Round 8
// 225.284 us; speedup vs baseline: 7.2453x; 1.3417x over previous
//
#include <hip/hip_runtime.h>
#include <math.h>

#define N_NODES 100000
#define IN_DIM 64
#define HID 128
#define HID2 64
#define N_EDGES 1600000
#define BN_EPS 1e-5f

// bucketing: 128 dst nodes per bucket
#define NPB 128
#define NB 782            // ceil(100000/128)
#define BIN_BLOCKS 391
#define BIN_CHUNK 4096    // 391*4096 >= 1.6M
#define SORT_CAP 4096     // bucket capacity for LDS sort (mean 2048, sigma ~45)

typedef __attribute__((ext_vector_type(8))) __bf16 bf16x8;
typedef __attribute__((ext_vector_type(4))) float f32x4;
typedef __attribute__((ext_vector_type(8))) unsigned short u16x8;

__device__ __forceinline__ unsigned short f2bf(float f) {
    unsigned int u = __builtin_bit_cast(unsigned int, f);
    u += 0x7fffu + ((u >> 16) & 1u);          // round-to-nearest-even
    return (unsigned short)(u >> 16);
}
__device__ __forceinline__ float bf2f(unsigned short h) {
    return __builtin_bit_cast(float, (unsigned int)h << 16);
}

// ---------------------------------------------------------------------------
// prep_wfrag: pack W1c=[W1l;W1r] (128x128) and W2c=[W2l|W2r] (128x128) into
// bf16 MFMA B-fragment order: Wf[((nt*4+kt)*64+lane)*8 + e] =
//   W[kt*32 + (lane>>4)*8 + e][nt*16 + (lane&15)]
// so a wave's B-frag load is 64 lanes x 16B contiguous (coalesced, L2-hit).
// ---------------------------------------------------------------------------
__global__ __launch_bounds__(256) void prep_wfrag(
    const float* __restrict__ W1l, const float* __restrict__ W1r,
    const float* __restrict__ W2l, const float* __restrict__ W2r,
    unsigned short* __restrict__ Wf1, unsigned short* __restrict__ Wf2)
{
    int task = blockIdx.x * 4 + (threadIdx.x >> 6);   // 0..63
    int lane = threadIdx.x & 63;
    int m  = task >> 5;          // 0: W1c, 1: W2c
    int nt = (task >> 2) & 7;
    int kt = task & 3;
    int col = nt * 16 + (lane & 15);
    int k0  = kt * 32 + (lane >> 4) * 8;
    unsigned short tmp[8];
    #pragma unroll
    for (int e = 0; e < 8; ++e) {
        int k = k0 + e;
        float v;
        if (m == 0) v = (k < 64) ? W1l[k * HID + col] : W1r[(k - 64) * HID + col];
        else        v = (col < 64) ? W2l[k * HID2 + col] : W2r[k * HID2 + (col - 64)];
        tmp[e] = f2bf(v);
    }
    unsigned short* dst = ((m == 0) ? Wf1 : Wf2)
                        + ((size_t)((nt * 4 + kt) * 64 + lane)) * 8;
    *(u16x8*)dst = *(const u16x8*)tmp;
}

// ---------------------------------------------------------------------------
// cast_x: Abuf[node][64+d] = bf16(x[node][d])   (x-half of combined A matrix)
// ---------------------------------------------------------------------------
__global__ __launch_bounds__(256) void cast_x(
    const float* __restrict__ x, unsigned short* __restrict__ Abuf)
{
    int tid = blockIdx.x * 256 + threadIdx.x;      // one per 4 elements
    if (tid >= N_NODES * 16) return;
    int node = tid >> 4;
    int q    = tid & 15;
    float4 v = ((const float4*)x)[tid];
    unsigned short o[4] = {f2bf(v.x), f2bf(v.y), f2bf(v.z), f2bf(v.w)};
    *(uint2*)(Abuf + (size_t)node * 128 + 64 + q * 4) = *(const uint2*)o;
}

// ---------------------------------------------------------------------------
// Binning pass 1: per-block bucket histogram; reserve per-(block,bucket) space
// ---------------------------------------------------------------------------
__global__ __launch_bounds__(256) void bin_count(
    const int* __restrict__ dst,
    int* __restrict__ bucketTotal,     // [NB] (zeroed)
    int* __restrict__ perBlockBase)    // [BIN_BLOCKS*NB]
{
    __shared__ int cnt[NB];
    const int t = threadIdx.x;
    for (int i = t; i < NB; i += 256) cnt[i] = 0;
    __syncthreads();
    const int e0 = blockIdx.x * BIN_CHUNK;
    for (int i = t; i < BIN_CHUNK; i += 256) {
        int e = e0 + i;
        if (e < N_EDGES) atomicAdd(&cnt[dst[e] >> 7], 1);
    }
    __syncthreads();
    for (int b = t; b < NB; b += 256) {
        int c = cnt[b];
        if (c) perBlockBase[blockIdx.x * NB + b] = atomicAdd(&bucketTotal[b], c);
    }
}

// ---------------------------------------------------------------------------
// Binning pass 2: exclusive scan of the 782 bucket totals (one block)
// ---------------------------------------------------------------------------
__global__ __launch_bounds__(1024) void bucket_scan(
    const int* __restrict__ bucketTotal, int* __restrict__ bucketStart)
{
    __shared__ int s[1024];
    const int t = threadIdx.x;
    int v = (t < NB) ? bucketTotal[t] : 0;
    s[t] = v;
    __syncthreads();
    #pragma unroll
    for (int off = 1; off < 1024; off <<= 1) {
        int u = (t >= off) ? s[t - off] : 0;
        __syncthreads();
        s[t] += u;
        __syncthreads();
    }
    if (t < NB) bucketStart[t] = s[t] - v;
    if (t == 0) bucketStart[NB] = N_EDGES;
}

// ---------------------------------------------------------------------------
// Binning pass 3: write packed (src<<7 | localDst) into bucket-grouped order
// ---------------------------------------------------------------------------
__global__ __launch_bounds__(256) void bin_write(
    const int* __restrict__ src, const int* __restrict__ dst,
    const int* __restrict__ bucketStart,
    const int* __restrict__ perBlockBase,
    unsigned int* __restrict__ binned)   // [E]
{
    __shared__ int cur[NB];
    const int t = threadIdx.x;
    for (int i = t; i < NB; i += 256) cur[i] = 0;
    __syncthreads();
    const int e0 = blockIdx.x * BIN_CHUNK;
    for (int i = t; i < BIN_CHUNK; i += 256) {
        int e = e0 + i;
        if (e < N_EDGES) {
            int d = dst[e];
            int b = d >> 7;
            int pos = bucketStart[b] + perBlockBase[blockIdx.x * NB + b]
                    + atomicAdd(&cur[b], 1);
            binned[pos] = ((unsigned int)src[e] << 7) | (unsigned int)(d & 127);
        }
    }
}

// ---------------------------------------------------------------------------
// bucket_sort: one block per bucket. Stage packed edges in LDS, 128-bin
// histogram + scan -> rowStart, then local scatter -> sortedSrc (contiguous
// coalesced run per block; no write amplification).
// ---------------------------------------------------------------------------
__global__ __launch_bounds__(256) void bucket_sort(
    const unsigned int* __restrict__ binned,
    const int* __restrict__ bucketStart,
    int* __restrict__ sortedSrc,      // [E]
    int* __restrict__ rowStart)       // [N+1]
{
    __shared__ unsigned int stage[SORT_CAP];
    __shared__ int hist[NPB];
    __shared__ int cur[NPB];

    const int b  = blockIdx.x;
    const int t  = threadIdx.x;
    const int bs = bucketStart[b];
    const int be = bucketStart[b + 1];
    const int total = be - bs;

    if (t < NPB) hist[t] = 0;
    __syncthreads();

    if (total <= SORT_CAP) {
        for (int i = t; i < total; i += 256) {
            unsigned int p = binned[bs + i];
            stage[i] = p;
            atomicAdd(&hist[p & 127], 1);
        }
        __syncthreads();
        int orig = (t < NPB) ? hist[t] : 0;
        __syncthreads();
        #pragma unroll
        for (int off = 1; off < NPB; off <<= 1) {
            int v = (t < NPB && t >= off) ? hist[t - off] : 0;
            __syncthreads();
            if (t < NPB) hist[t] += v;
            __syncthreads();
        }
        if (t < NPB) {
            int excl = hist[t] - orig;
            int node = b * NPB + t;
            if (node < N_NODES) rowStart[node] = bs + excl;
            cur[t] = excl;
        }
        if (b == 0 && t == 0) rowStart[N_NODES] = N_EDGES;
        __syncthreads();
        for (int i = t; i < total; i += 256) {
            unsigned int p = stage[i];
            int pos = atomicAdd(&cur[p & 127], 1);
            sortedSrc[bs + pos] = (int)(p >> 7);
        }
    } else {
        for (int i = t; i < total; i += 256)
            atomicAdd(&hist[binned[bs + i] & 127], 1);
        __syncthreads();
        int orig = (t < NPB) ? hist[t] : 0;
        __syncthreads();
        #pragma unroll
        for (int off = 1; off < NPB; off <<= 1) {
            int v = (t < NPB && t >= off) ? hist[t - off] : 0;
            __syncthreads();
            if (t < NPB) hist[t] += v;
            __syncthreads();
        }
        if (t < NPB) {
            int excl = hist[t] - orig;
            int node = b * NPB + t;
            if (node < N_NODES) rowStart[node] = bs + excl;
            cur[t] = excl;
        }
        if (b == 0 && t == 0) rowStart[N_NODES] = N_EDGES;
        __syncthreads();
        for (int i = t; i < total; i += 256) {
            unsigned int p = binned[bs + i];
            int pos = atomicAdd(&cur[p & 127], 1);
            sortedSrc[bs + pos] = (int)(p >> 7);
        }
    }
}

// ---------------------------------------------------------------------------
// gather1: one wave per node, lane = feature; mean of fp32 x rows -> bf16
// into the mean-half of Abuf. 8 independent accumulators.
// ---------------------------------------------------------------------------
__global__ __launch_bounds__(256) void gather_mean_bf16(
    const float* __restrict__ feat,      // [N,64] fp32 (x)
    const int* __restrict__ rowStart,    // [N+1]
    const int* __restrict__ sortedSrc,   // [E]
    unsigned short* __restrict__ Abuf)   // [N,128] bf16, writes cols [0,64)
{
    int node = (int)((blockIdx.x * 256u + threadIdx.x) >> 6);
    int lane = threadIdx.x & 63;
    if (node >= N_NODES) return;
    int b = rowStart[node];
    int e = rowStart[node + 1];
    float a0 = 0.f, a1 = 0.f, a2 = 0.f, a3 = 0.f;
    float a4 = 0.f, a5 = 0.f, a6 = 0.f, a7 = 0.f;
    int j = b;
    for (; j + 8 <= e; j += 8) {
        int s0 = sortedSrc[j + 0];
        int s1 = sortedSrc[j + 1];
        int s2 = sortedSrc[j + 2];
        int s3 = sortedSrc[j + 3];
        int s4 = sortedSrc[j + 4];
        int s5 = sortedSrc[j + 5];
        int s6 = sortedSrc[j + 6];
        int s7 = sortedSrc[j + 7];
        a0 += feat[(size_t)s0 * 64 + lane];
        a1 += feat[(size_t)s1 * 64 + lane];
        a2 += feat[(size_t)s2 * 64 + lane];
        a3 += feat[(size_t)s3 * 64 + lane];
        a4 += feat[(size_t)s4 * 64 + lane];
        a5 += feat[(size_t)s5 * 64 + lane];
        a6 += feat[(size_t)s6 * 64 + lane];
        a7 += feat[(size_t)s7 * 64 + lane];
    }
    for (; j < e; ++j) a0 += feat[(size_t)sortedSrc[j] * 64 + lane];
    float sum = ((a0 + a1) + (a2 + a3)) + ((a4 + a5) + (a6 + a7));
    float inv = 1.0f / fmaxf((float)(e - b), 1.0f);
    Abuf[(size_t)node * 128 + lane] = f2bf(sum * inv);
}

// ---------------------------------------------------------------------------
// gemm_fused_mfma: 64 nodes/block, both layers' dense math via MFMA bf16.
//   GEMM1: pre = Abuf([mean|x]) @ W1c     (K=128, N=128)
//   epi1 : h1 = relu(bn1(pre)) -> back into the same LDS (bf16)
//   GEMM2: [t1|r1] = h1 @ W2c             (K=128, N=128)
// LDS: Al[64][136] bf16 = 17.4 KB. A-frag: lane l -> row=l&15, k=(l>>4)*8.
// B-frags stream from fragment-ordered Wf buffers (coalesced, L2-resident).
// C/D frag (m89): col = lane&15, row = (lane>>4)*4 + reg.
// Wave w owns output cols [32w, 32w+32) (nt = 2w, 2w+1).
// ---------------------------------------------------------------------------
__global__ __launch_bounds__(256, 4) void gemm_fused_mfma(
    const unsigned short* __restrict__ Abuf,   // [N,128] bf16
    const unsigned short* __restrict__ Wf1,
    const unsigned short* __restrict__ Wf2,
    const float* __restrict__ b1l,
    const float* __restrict__ g1, const float* __restrict__ be1,
    const float* __restrict__ m1, const float* __restrict__ v1,
    unsigned short* __restrict__ t1,           // [N,64] bf16
    float* __restrict__ r1)                    // [N,64] fp32
{
    __shared__ unsigned short Al[64 * 136];    // row stride 272B (17x16B)

    const int t = threadIdx.x;
    const int w = t >> 6, l = t & 63;
    const int n0 = blockIdx.x * 64;

    // ---- stage A: copy 64 x 256B bf16 rows into padded LDS ----
    {
        const int node = t >> 2, q = t & 3;
        const int nn = n0 + node;
        const uint4* srcp = (const uint4*)(Abuf + (size_t)nn * 128) + q * 4;
        uint4 z; z.x = z.y = z.z = z.w = 0u;
        unsigned short* drow = &Al[node * 136 + q * 32];
        #pragma unroll
        for (int i = 0; i < 4; ++i) {
            uint4 v = (nn < N_NODES) ? srcp[i] : z;
            *(uint4*)(drow + i * 8) = v;
        }
    }
    __syncthreads();

    const int row = l & 15, kq = l >> 4;

    // ---- GEMM1 ----
    f32x4 acc[4][2];
    #pragma unroll
    for (int a = 0; a < 4; ++a)
        #pragma unroll
        for (int b = 0; b < 2; ++b) acc[a][b] = (f32x4)(0.0f);

    #pragma unroll
    for (int kt = 0; kt < 4; ++kt) {
        bf16x8 bfr[2];
        #pragma unroll
        for (int n = 0; n < 2; ++n)
            bfr[n] = __builtin_bit_cast(bf16x8,
                *(const u16x8*)(Wf1 + ((size_t)(((2 * w + n) * 4 + kt) * 64 + l)) * 8));
        #pragma unroll
        for (int mt = 0; mt < 4; ++mt) {
            bf16x8 afr = __builtin_bit_cast(bf16x8,
                *(const u16x8*)&Al[(mt * 16 + row) * 136 + kt * 32 + kq * 8]);
            #pragma unroll
            for (int n = 0; n < 2; ++n)
                acc[mt][n] = __builtin_amdgcn_mfma_f32_16x16x32_bf16(
                    afr, bfr[n], acc[mt][n], 0, 0, 0);
        }
    }
    __syncthreads();   // all reads of A done before h1 overwrites

    // ---- epilogue 1: h1 = relu(bn1(pre)) -> Al (bf16) ----
    #pragma unroll
    for (int n = 0; n < 2; ++n) {
        int j = w * 32 + n * 16 + (l & 15);
        float s  = g1[j] * rsqrtf(v1[j] + BN_EPS);
        float of = be1[j] + (b1l[j] - m1[j]) * s;
        #pragma unroll
        for (int mt = 0; mt < 4; ++mt) {
            #pragma unroll
            for (int i = 0; i < 4; ++i) {
                float h = fmaxf(fmaf(acc[mt][n][i], s, of), 0.0f);
                Al[(mt * 16 + kq * 4 + i) * 136 + j] = f2bf(h);
            }
        }
    }
    __syncthreads();

    // ---- GEMM2 ----
    f32x4 acc2[4][2];
    #pragma unroll
    for (int a = 0; a < 4; ++a)
        #pragma unroll
        for (int b = 0; b < 2; ++b) acc2[a][b] = (f32x4)(0.0f);

    #pragma unroll
    for (int kt = 0; kt < 4; ++kt) {
        bf16x8 bfr[2];
        #pragma unroll
        for (int n = 0; n < 2; ++n)
            bfr[n] = __builtin_bit_cast(bf16x8,
                *(const u16x8*)(Wf2 + ((size_t)(((2 * w + n) * 4 + kt) * 64 + l)) * 8));
        #pragma unroll
        for (int mt = 0; mt < 4; ++mt) {
            bf16x8 afr = __builtin_bit_cast(bf16x8,
                *(const u16x8*)&Al[(mt * 16 + row) * 136 + kt * 32 + kq * 8]);
            #pragma unroll
            for (int n = 0; n < 2; ++n)
                acc2[mt][n] = __builtin_amdgcn_mfma_f32_16x16x32_bf16(
                    afr, bfr[n], acc2[mt][n], 0, 0, 0);
        }
    }

    // ---- epilogue 2: cols [0,64) -> t1 (bf16), [64,128) -> r1 (fp32) ----
    #pragma unroll
    for (int n = 0; n < 2; ++n) {
        int j = w * 32 + n * 16 + (l & 15);
        #pragma unroll
        for (int mt = 0; mt < 4; ++mt) {
            #pragma unroll
            for (int i = 0; i < 4; ++i) {
                int node = n0 + mt * 16 + kq * 4 + i;
                if (node < N_NODES) {
                    float vv = acc2[mt][n][i];
                    if (w < 2) t1[(size_t)node * 64 + j] = f2bf(vv);
                    else       r1[(size_t)node * 64 + (j - 64)] = vv;
                }
            }
        }
    }
}

// ---------------------------------------------------------------------------
// gather2_fused: mean of bf16 t1 rows + b2l + r1, BN2, ReLU, classifier.
// ---------------------------------------------------------------------------
__global__ __launch_bounds__(256) void gather2_fused(
    const unsigned short* __restrict__ t1,   // [N,64] bf16
    const int* __restrict__ rowStart,
    const int* __restrict__ sortedSrc,
    const float* __restrict__ r1,            // [N,64] fp32
    const float* __restrict__ b2l,
    const float* __restrict__ g2, const float* __restrict__ be2,
    const float* __restrict__ m2, const float* __restrict__ v2,
    const float* __restrict__ Wc, const float* __restrict__ bc,
    float* __restrict__ out)                 // [N,2]
{
    int node = (int)((blockIdx.x * 256u + threadIdx.x) >> 6);
    int lane = threadIdx.x & 63;
    if (node >= N_NODES) return;
    int b = rowStart[node];
    int e = rowStart[node + 1];
    float a0 = 0.f, a1 = 0.f, a2 = 0.f, a3 = 0.f;
    float a4 = 0.f, a5 = 0.f, a6 = 0.f, a7 = 0.f;
    int j = b;
    for (; j + 8 <= e; j += 8) {
        int s0 = sortedSrc[j + 0];
        int s1 = sortedSrc[j + 1];
        int s2 = sortedSrc[j + 2];
        int s3 = sortedSrc[j + 3];
        int s4 = sortedSrc[j + 4];
        int s5 = sortedSrc[j + 5];
        int s6 = sortedSrc[j + 6];
        int s7 = sortedSrc[j + 7];
        a0 += bf2f(t1[(size_t)s0 * 64 + lane]);
        a1 += bf2f(t1[(size_t)s1 * 64 + lane]);
        a2 += bf2f(t1[(size_t)s2 * 64 + lane]);
        a3 += bf2f(t1[(size_t)s3 * 64 + lane]);
        a4 += bf2f(t1[(size_t)s4 * 64 + lane]);
        a5 += bf2f(t1[(size_t)s5 * 64 + lane]);
        a6 += bf2f(t1[(size_t)s6 * 64 + lane]);
        a7 += bf2f(t1[(size_t)s7 * 64 + lane]);
    }
    for (; j < e; ++j) a0 += bf2f(t1[(size_t)sortedSrc[j] * 64 + lane]);
    float sum = ((a0 + a1) + (a2 + a3)) + ((a4 + a5) + (a6 + a7));
    float inv = 1.0f / fmaxf((float)(e - b), 1.0f);
    float mv  = sum * inv;

    float pre = mv + b2l[lane] + r1[(size_t)node * 64 + lane];
    float s   = g2[lane] * rsqrtf(v2[lane] + BN_EPS);
    float h2  = fmaxf((pre - m2[lane]) * s + be2[lane], 0.0f);
    float l0 = h2 * Wc[lane * 2 + 0];
    float l1 = h2 * Wc[lane * 2 + 1];
    #pragma unroll
    for (int off = 32; off > 0; off >>= 1) {
        l0 += __shfl_xor(l0, off);
        l1 += __shfl_xor(l1, off);
    }
    if (lane == 0) {
        out[(size_t)node * 2 + 0] = l0 + bc[0];
        out[(size_t)node * 2 + 1] = l1 + bc[1];
    }
}

// ---------------------------------------------------------------------------
extern "C" void kernel_launch(void* const* d_in, const int* in_sizes, int n_in,
                              void* d_out, int out_size, void* d_ws, size_t ws_size,
                              hipStream_t stream)
{
    const float* x    = (const float*)d_in[0];
    const int*   eidx = (const int*)d_in[1];   // [2, E]: row 0 = src, row 1 = dst
    const float* W1l  = (const float*)d_in[2];
    const float* b1l  = (const float*)d_in[3];
    const float* W1r  = (const float*)d_in[4];
    const float* W2l  = (const float*)d_in[5];
    const float* b2l  = (const float*)d_in[6];
    const float* W2r  = (const float*)d_in[7];
    const float* g1   = (const float*)d_in[8];
    const float* be1  = (const float*)d_in[9];
    const float* m1   = (const float*)d_in[10];
    const float* v1   = (const float*)d_in[11];
    const float* g2   = (const float*)d_in[12];
    const float* be2  = (const float*)d_in[13];
    const float* m2   = (const float*)d_in[14];
    const float* v2   = (const float*)d_in[15];
    const float* Wc   = (const float*)d_in[16];
    const float* bc   = (const float*)d_in[17];
    float* out = (float*)d_out;

    const int* src = eidx;
    const int* dst = eidx + N_EDGES;

    // ---- workspace layout ----
    char* ws = (char*)d_ws;
    size_t off = 0;
    auto alloc = [&](size_t bytes) { void* p = ws + off; off = (off + bytes + 255) & ~(size_t)255; return p; };
    int* bucketTotal  = (int*)alloc((size_t)NB * 4);
    int* bucketStart  = (int*)alloc((size_t)(NB + 1) * 4);
    int* perBlockBase = (int*)alloc((size_t)BIN_BLOCKS * NB * 4);
    unsigned int* binned = (unsigned int*)alloc((size_t)N_EDGES * 4);
    int* sortedSrc    = (int*)alloc((size_t)N_EDGES * 4);
    int* rowStart     = (int*)alloc((size_t)(N_NODES + 1) * 4);
    unsigned short* Wf1  = (unsigned short*)alloc(128 * 128 * 2);
    unsigned short* Wf2  = (unsigned short*)alloc(128 * 128 * 2);
    unsigned short* Abuf = (unsigned short*)alloc((size_t)N_NODES * 128 * 2);
    unsigned short* t1   = (unsigned short*)alloc((size_t)N_NODES * 64 * 2);
    float* r1            = (float*)alloc((size_t)N_NODES * 64 * 4);

    const int gemmGrid     = (N_NODES + 63) / 64;            // 1563
    const int nodeWaveGrid = (N_NODES * 64 + 255) / 256;     // 25000

    // ---- prep (off critical path, tiny) ----
    prep_wfrag<<<16, 256, 0, stream>>>(W1l, W1r, W2l, W2r, Wf1, Wf2);
    cast_x<<<(N_NODES * 16 + 255) / 256, 256, 0, stream>>>(x, Abuf);

    // ---- counting sort of edges by dst ----
    hipMemsetAsync(bucketTotal, 0, (size_t)NB * 4, stream);
    bin_count  <<<BIN_BLOCKS, 256, 0, stream>>>(dst, bucketTotal, perBlockBase);
    bucket_scan<<<1, 1024, 0, stream>>>(bucketTotal, bucketStart);
    bin_write  <<<BIN_BLOCKS, 256, 0, stream>>>(src, dst, bucketStart, perBlockBase, binned);
    bucket_sort<<<NB, 256, 0, stream>>>(binned, bucketStart, sortedSrc, rowStart);

    // ---- layer 1: mean (bf16) -> Abuf cols [0,64) ----
    gather_mean_bf16<<<nodeWaveGrid, 256, 0, stream>>>(x, rowStart, sortedSrc, Abuf);

    // ---- fused dense (MFMA): h1 internal -> t1 (bf16), r1 (fp32) ----
    gemm_fused_mfma<<<gemmGrid, 256, 0, stream>>>(
        Abuf, Wf1, Wf2, b1l, g1, be1, m1, v1, t1, r1);

    // ---- layer 2: gather t1 + fused BN2/ReLU/classifier -> out ----
    gather2_fused<<<nodeWaveGrid, 256, 0, stream>>>(
        t1, rowStart, sortedSrc, r1, b2l, g2, be2, m2, v2, Wc, bc, out);
}

// Round 9
// 187.588 us; speedup vs baseline: 8.7013x; 1.2010x over previous
//
#include <hip/hip_runtime.h>
#include <math.h>

#define N_NODES 100000
#define IN_DIM 64
#define HID 128
#define HID2 64
#define N_EDGES 1600000
#define BN_EPS 1e-5f

// bucketing: 128 dst nodes per bucket
#define NPB 128
#define NB 782            // ceil(100000/128)
#define BIN_BLOCKS 391
#define BIN_CHUNK 4096    // 391*4096 >= 1.6M
#define SORT_CAP 4096     // bucket capacity for LDS sort (mean 2048, sigma ~45)

typedef __attribute__((ext_vector_type(8))) __bf16 bf16x8;
typedef __attribute__((ext_vector_type(4))) float f32x4;
typedef __attribute__((ext_vector_type(8))) unsigned short u16x8;

__device__ __forceinline__ unsigned short f2bf(float f) {
    unsigned int u = __builtin_bit_cast(unsigned int, f);
    u += 0x7fffu + ((u >> 16) & 1u);          // round-to-nearest-even
    return (unsigned short)(u >> 16);
}
__device__ __forceinline__ float bf2f(unsigned short h) {
    return __builtin_bit_cast(float, (unsigned int)h << 16);
}

// ---------------------------------------------------------------------------
// prep_wfrag: pack W1c=[W1l;W1r] (128x128) and W2c=[W2l|W2r] (128x128) into
// bf16 MFMA B-fragment order (coalesced 16B/lane frag loads).
// ---------------------------------------------------------------------------
__global__ __launch_bounds__(256) void prep_wfrag(
    const float* __restrict__ W1l, const float* __restrict__ W1r,
    const float* __restrict__ W2l, const float* __restrict__ W2r,
    unsigned short* __restrict__ Wf1, unsigned short* __restrict__ Wf2)
{
    int task = blockIdx.x * 4 + (threadIdx.x >> 6);   // 0..63
    int lane = threadIdx.x & 63;
    int m  = task >> 5;          // 0: W1c, 1: W2c
    int nt = (task >> 2) & 7;
    int kt = task & 3;
    int col = nt * 16 + (lane & 15);
    int k0  = kt * 32 + (lane >> 4) * 8;
    unsigned short tmp[8];
    #pragma unroll
    for (int e = 0; e < 8; ++e) {
        int k = k0 + e;
        float v;
        if (m == 0) v = (k < 64) ? W1l[k * HID + col] : W1r[(k - 64) * HID + col];
        else        v = (col < 64) ? W2l[k * HID2 + col] : W2r[k * HID2 + (col - 64)];
        tmp[e] = f2bf(v);
    }
    unsigned short* dst = ((m == 0) ? Wf1 : Wf2)
                        + ((size_t)((nt * 4 + kt) * 64 + lane)) * 8;
    *(u16x8*)dst = *(const u16x8*)tmp;
}

// ---------------------------------------------------------------------------
// cast_x: Abuf[node][64+d] = bf16(x[node][d])   (x-half of combined A matrix)
// ---------------------------------------------------------------------------
__global__ __launch_bounds__(256) void cast_x(
    const float* __restrict__ x, unsigned short* __restrict__ Abuf)
{
    int tid = blockIdx.x * 256 + threadIdx.x;      // one per 4 elements
    if (tid >= N_NODES * 16) return;
    int node = tid >> 4;
    int q    = tid & 15;
    float4 v = ((const float4*)x)[tid];
    unsigned short o[4] = {f2bf(v.x), f2bf(v.y), f2bf(v.z), f2bf(v.w)};
    *(uint2*)(Abuf + (size_t)node * 128 + 64 + q * 4) = *(const uint2*)o;
}

// ---------------------------------------------------------------------------
// Binning pass 1: per-block bucket histogram; reserve per-(block,bucket) space
// ---------------------------------------------------------------------------
__global__ __launch_bounds__(256) void bin_count(
    const int* __restrict__ dst,
    int* __restrict__ bucketTotal,     // [NB] (zeroed)
    int* __restrict__ perBlockBase)    // [BIN_BLOCKS*NB]
{
    __shared__ int cnt[NB];
    const int t = threadIdx.x;
    for (int i = t; i < NB; i += 256) cnt[i] = 0;
    __syncthreads();
    const int e0 = blockIdx.x * BIN_CHUNK;
    for (int i = t; i < BIN_CHUNK; i += 256) {
        int e = e0 + i;
        if (e < N_EDGES) atomicAdd(&cnt[dst[e] >> 7], 1);
    }
    __syncthreads();
    for (int b = t; b < NB; b += 256) {
        int c = cnt[b];
        if (c) perBlockBase[blockIdx.x * NB + b] = atomicAdd(&bucketTotal[b], c);
    }
}

// ---------------------------------------------------------------------------
// Binning pass 2: exclusive scan of the 782 bucket totals (one block)
// ---------------------------------------------------------------------------
__global__ __launch_bounds__(1024) void bucket_scan(
    const int* __restrict__ bucketTotal, int* __restrict__ bucketStart)
{
    __shared__ int s[1024];
    const int t = threadIdx.x;
    int v = (t < NB) ? bucketTotal[t] : 0;
    s[t] = v;
    __syncthreads();
    #pragma unroll
    for (int off = 1; off < 1024; off <<= 1) {
        int u = (t >= off) ? s[t - off] : 0;
        __syncthreads();
        s[t] += u;
        __syncthreads();
    }
    if (t < NB) bucketStart[t] = s[t] - v;
    if (t == 0) bucketStart[NB] = N_EDGES;
}

// ---------------------------------------------------------------------------
// Binning pass 3: write packed (src<<7 | localDst) into bucket-grouped order
// ---------------------------------------------------------------------------
__global__ __launch_bounds__(256) void bin_write(
    const int* __restrict__ src, const int* __restrict__ dst,
    const int* __restrict__ bucketStart,
    const int* __restrict__ perBlockBase,
    unsigned int* __restrict__ binned)   // [E]
{
    __shared__ int cur[NB];
    const int t = threadIdx.x;
    for (int i = t; i < NB; i += 256) cur[i] = 0;
    __syncthreads();
    const int e0 = blockIdx.x * BIN_CHUNK;
    for (int i = t; i < BIN_CHUNK; i += 256) {
        int e = e0 + i;
        if (e < N_EDGES) {
            int d = dst[e];
            int b = d >> 7;
            int pos = bucketStart[b] + perBlockBase[blockIdx.x * NB + b]
                    + atomicAdd(&cur[b], 1);
            binned[pos] = ((unsigned int)src[e] << 7) | (unsigned int)(d & 127);
        }
    }
}

// ---------------------------------------------------------------------------
// bucket_sort: one block per bucket. Stage packed edges in LDS, 128-bin
// histogram + scan -> rowStart, then local scatter -> sortedSrc (contiguous
// coalesced run per block; no write amplification).
// ---------------------------------------------------------------------------
__global__ __launch_bounds__(256) void bucket_sort(
    const unsigned int* __restrict__ binned,
    const int* __restrict__ bucketStart,
    int* __restrict__ sortedSrc,      // [E]
    int* __restrict__ rowStart)       // [N+1]
{
    __shared__ unsigned int stage[SORT_CAP];
    __shared__ int hist[NPB];
    __shared__ int cur[NPB];

    const int b  = blockIdx.x;
    const int t  = threadIdx.x;
    const int bs = bucketStart[b];
    const int be = bucketStart[b + 1];
    const int total = be - bs;

    if (t < NPB) hist[t] = 0;
    __syncthreads();

    if (total <= SORT_CAP) {
        for (int i = t; i < total; i += 256) {
            unsigned int p = binned[bs + i];
            stage[i] = p;
            atomicAdd(&hist[p & 127], 1);
        }
        __syncthreads();
        int orig = (t < NPB) ? hist[t] : 0;
        __syncthreads();
        #pragma unroll
        for (int off = 1; off < NPB; off <<= 1) {
            int v = (t < NPB && t >= off) ? hist[t - off] : 0;
            __syncthreads();
            if (t < NPB) hist[t] += v;
            __syncthreads();
        }
        if (t < NPB) {
            int excl = hist[t] - orig;
            int node = b * NPB + t;
            if (node < N_NODES) rowStart[node] = bs + excl;
            cur[t] = excl;
        }
        if (b == 0 && t == 0) rowStart[N_NODES] = N_EDGES;
        __syncthreads();
        for (int i = t; i < total; i += 256) {
            unsigned int p = stage[i];
            int pos = atomicAdd(&cur[p & 127], 1);
            sortedSrc[bs + pos] = (int)(p >> 7);
        }
    } else {
        for (int i = t; i < total; i += 256)
            atomicAdd(&hist[binned[bs + i] & 127], 1);
        __syncthreads();
        int orig = (t < NPB) ? hist[t] : 0;
        __syncthreads();
        #pragma unroll
        for (int off = 1; off < NPB; off <<= 1) {
            int v = (t < NPB && t >= off) ? hist[t - off] : 0;
            __syncthreads();
            if (t < NPB) hist[t] += v;
            __syncthreads();
        }
        if (t < NPB) {
            int excl = hist[t] - orig;
            int node = b * NPB + t;
            if (node < N_NODES) rowStart[node] = bs + excl;
            cur[t] = excl;
        }
        if (b == 0 && t == 0) rowStart[N_NODES] = N_EDGES;
        __syncthreads();
        for (int i = t; i < total; i += 256) {
            unsigned int p = binned[bs + i];
            int pos = atomicAdd(&cur[p & 127], 1);
            sortedSrc[bs + pos] = (int)(p >> 7);
        }
    }
}

// ---------------------------------------------------------------------------
// gather1: wave per node; slot = lane>>4 owns every-4th edge, q = lane&15
// loads uint2 (4 bf16 features) -> one VMEM instr covers 4 edges x 128B.
// Reads the bf16 x-half of Abuf; writes bf16 mean into cols [0,64).
// ---------------------------------------------------------------------------
__global__ __launch_bounds__(256) void gather1_v2(
    const int* __restrict__ rowStart,
    const int* __restrict__ sortedSrc,
    unsigned short* __restrict__ Abuf)   // [N,128] bf16: [mean|x]
{
    int node = (int)((blockIdx.x * 256u + threadIdx.x) >> 6);
    int lane = threadIdx.x & 63;
    if (node >= N_NODES) return;
    const int slot = lane >> 4, q = lane & 15;
    const int b = rowStart[node], e = rowStart[node + 1];

    float a0 = 0.f, a1 = 0.f, a2 = 0.f, a3 = 0.f;
    float c0 = 0.f, c1 = 0.f, c2 = 0.f, c3 = 0.f;
    int j = b + slot;
    for (; j + 4 < e; j += 8) {
        int s0 = sortedSrc[j];
        int s1 = sortedSrc[j + 4];
        uint2 v0 = *(const uint2*)(Abuf + (size_t)s0 * 128 + 64 + q * 4);
        uint2 v1 = *(const uint2*)(Abuf + (size_t)s1 * 128 + 64 + q * 4);
        const unsigned short* p0 = (const unsigned short*)&v0;
        const unsigned short* p1 = (const unsigned short*)&v1;
        a0 += bf2f(p0[0]); a1 += bf2f(p0[1]); a2 += bf2f(p0[2]); a3 += bf2f(p0[3]);
        c0 += bf2f(p1[0]); c1 += bf2f(p1[1]); c2 += bf2f(p1[2]); c3 += bf2f(p1[3]);
    }
    if (j < e) {
        int s0 = sortedSrc[j];
        uint2 v0 = *(const uint2*)(Abuf + (size_t)s0 * 128 + 64 + q * 4);
        const unsigned short* p0 = (const unsigned short*)&v0;
        a0 += bf2f(p0[0]); a1 += bf2f(p0[1]); a2 += bf2f(p0[2]); a3 += bf2f(p0[3]);
    }
    a0 += c0; a1 += c1; a2 += c2; a3 += c3;
    a0 += __shfl_xor(a0, 16); a0 += __shfl_xor(a0, 32);
    a1 += __shfl_xor(a1, 16); a1 += __shfl_xor(a1, 32);
    a2 += __shfl_xor(a2, 16); a2 += __shfl_xor(a2, 32);
    a3 += __shfl_xor(a3, 16); a3 += __shfl_xor(a3, 32);

    if (slot == 0) {
        float inv = 1.0f / fmaxf((float)(e - b), 1.0f);
        unsigned short o[4] = {f2bf(a0 * inv), f2bf(a1 * inv),
                               f2bf(a2 * inv), f2bf(a3 * inv)};
        *(uint2*)(Abuf + (size_t)node * 128 + q * 4) = *(const uint2*)o;
    }
}

// ---------------------------------------------------------------------------
// gemm_fused_mfma: 64 nodes/block, both layers' dense math via MFMA bf16.
// ---------------------------------------------------------------------------
__global__ __launch_bounds__(256, 4) void gemm_fused_mfma(
    const unsigned short* __restrict__ Abuf,   // [N,128] bf16
    const unsigned short* __restrict__ Wf1,
    const unsigned short* __restrict__ Wf2,
    const float* __restrict__ b1l,
    const float* __restrict__ g1, const float* __restrict__ be1,
    const float* __restrict__ m1, const float* __restrict__ v1,
    unsigned short* __restrict__ t1,           // [N,64] bf16
    float* __restrict__ r1)                    // [N,64] fp32
{
    __shared__ unsigned short Al[64 * 136];    // row stride 272B (17x16B)

    const int t = threadIdx.x;
    const int w = t >> 6, l = t & 63;
    const int n0 = blockIdx.x * 64;

    // ---- stage A: copy 64 x 256B bf16 rows into padded LDS ----
    {
        const int node = t >> 2, q = t & 3;
        const int nn = n0 + node;
        const uint4* srcp = (const uint4*)(Abuf + (size_t)nn * 128) + q * 4;
        uint4 z; z.x = z.y = z.z = z.w = 0u;
        unsigned short* drow = &Al[node * 136 + q * 32];
        #pragma unroll
        for (int i = 0; i < 4; ++i) {
            uint4 v = (nn < N_NODES) ? srcp[i] : z;
            *(uint4*)(drow + i * 8) = v;
        }
    }
    __syncthreads();

    const int row = l & 15, kq = l >> 4;

    // ---- GEMM1 ----
    f32x4 acc[4][2];
    #pragma unroll
    for (int a = 0; a < 4; ++a)
        #pragma unroll
        for (int b = 0; b < 2; ++b) acc[a][b] = (f32x4)(0.0f);

    #pragma unroll
    for (int kt = 0; kt < 4; ++kt) {
        bf16x8 bfr[2];
        #pragma unroll
        for (int n = 0; n < 2; ++n)
            bfr[n] = __builtin_bit_cast(bf16x8,
                *(const u16x8*)(Wf1 + ((size_t)(((2 * w + n) * 4 + kt) * 64 + l)) * 8));
        #pragma unroll
        for (int mt = 0; mt < 4; ++mt) {
            bf16x8 afr = __builtin_bit_cast(bf16x8,
                *(const u16x8*)&Al[(mt * 16 + row) * 136 + kt * 32 + kq * 8]);
            #pragma unroll
            for (int n = 0; n < 2; ++n)
                acc[mt][n] = __builtin_amdgcn_mfma_f32_16x16x32_bf16(
                    afr, bfr[n], acc[mt][n], 0, 0, 0);
        }
    }
    __syncthreads();   // all reads of A done before h1 overwrites

    // ---- epilogue 1: h1 = relu(bn1(pre)) -> Al (bf16) ----
    #pragma unroll
    for (int n = 0; n < 2; ++n) {
        int j = w * 32 + n * 16 + (l & 15);
        float s  = g1[j] * rsqrtf(v1[j] + BN_EPS);
        float of = be1[j] + (b1l[j] - m1[j]) * s;
        #pragma unroll
        for (int mt = 0; mt < 4; ++mt) {
            #pragma unroll
            for (int i = 0; i < 4; ++i) {
                float h = fmaxf(fmaf(acc[mt][n][i], s, of), 0.0f);
                Al[(mt * 16 + kq * 4 + i) * 136 + j] = f2bf(h);
            }
        }
    }
    __syncthreads();

    // ---- GEMM2 ----
    f32x4 acc2[4][2];
    #pragma unroll
    for (int a = 0; a < 4; ++a)
        #pragma unroll
        for (int b = 0; b < 2; ++b) acc2[a][b] = (f32x4)(0.0f);

    #pragma unroll
    for (int kt = 0; kt < 4; ++kt) {
        bf16x8 bfr[2];
        #pragma unroll
        for (int n = 0; n < 2; ++n)
            bfr[n] = __builtin_bit_cast(bf16x8,
                *(const u16x8*)(Wf2 + ((size_t)(((2 * w + n) * 4 + kt) * 64 + l)) * 8));
        #pragma unroll
        for (int mt = 0; mt < 4; ++mt) {
            bf16x8 afr = __builtin_bit_cast(bf16x8,
                *(const u16x8*)&Al[(mt * 16 + row) * 136 + kt * 32 + kq * 8]);
            #pragma unroll
            for (int n = 0; n < 2; ++n)
                acc2[mt][n] = __builtin_amdgcn_mfma_f32_16x16x32_bf16(
                    afr, bfr[n], acc2[mt][n], 0, 0, 0);
        }
    }

    // ---- epilogue 2: cols [0,64) -> t1 (bf16), [64,128) -> r1 (fp32) ----
    #pragma unroll
    for (int n = 0; n < 2; ++n) {
        int j = w * 32 + n * 16 + (l & 15);
        #pragma unroll
        for (int mt = 0; mt < 4; ++mt) {
            #pragma unroll
            for (int i = 0; i < 4; ++i) {
                int node = n0 + mt * 16 + kq * 4 + i;
                if (node < N_NODES) {
                    float vv = acc2[mt][n][i];
                    if (w < 2) t1[(size_t)node * 64 + j] = f2bf(vv);
                    else       r1[(size_t)node * 64 + (j - 64)] = vv;
                }
            }
        }
    }
}

// ---------------------------------------------------------------------------
// gather2: same 4-edges-per-instr layout on bf16 t1 rows + fused epilogue
// (BN2, ReLU, classifier).
// ---------------------------------------------------------------------------
__global__ __launch_bounds__(256) void gather2_v2(
    const unsigned short* __restrict__ t1,   // [N,64] bf16
    const int* __restrict__ rowStart,
    const int* __restrict__ sortedSrc,
    const float* __restrict__ r1,            // [N,64] fp32
    const float* __restrict__ b2l,
    const float* __restrict__ g2, const float* __restrict__ be2,
    const float* __restrict__ m2, const float* __restrict__ v2,
    const float* __restrict__ Wc, const float* __restrict__ bc,
    float* __restrict__ out)                 // [N,2]
{
    int node = (int)((blockIdx.x * 256u + threadIdx.x) >> 6);
    int lane = threadIdx.x & 63;
    if (node >= N_NODES) return;
    const int slot = lane >> 4, q = lane & 15;
    const int b = rowStart[node], e = rowStart[node + 1];

    float a0 = 0.f, a1 = 0.f, a2 = 0.f, a3 = 0.f;
    float c0 = 0.f, c1 = 0.f, c2 = 0.f, c3 = 0.f;
    int j = b + slot;
    for (; j + 4 < e; j += 8) {
        int s0 = sortedSrc[j];
        int s1 = sortedSrc[j + 4];
        uint2 v0 = *(const uint2*)(t1 + (size_t)s0 * 64 + q * 4);
        uint2 v1 = *(const uint2*)(t1 + (size_t)s1 * 64 + q * 4);
        const unsigned short* p0 = (const unsigned short*)&v0;
        const unsigned short* p1 = (const unsigned short*)&v1;
        a0 += bf2f(p0[0]); a1 += bf2f(p0[1]); a2 += bf2f(p0[2]); a3 += bf2f(p0[3]);
        c0 += bf2f(p1[0]); c1 += bf2f(p1[1]); c2 += bf2f(p1[2]); c3 += bf2f(p1[3]);
    }
    if (j < e) {
        int s0 = sortedSrc[j];
        uint2 v0 = *(const uint2*)(t1 + (size_t)s0 * 64 + q * 4);
        const unsigned short* p0 = (const unsigned short*)&v0;
        a0 += bf2f(p0[0]); a1 += bf2f(p0[1]); a2 += bf2f(p0[2]); a3 += bf2f(p0[3]);
    }
    a0 += c0; a1 += c1; a2 += c2; a3 += c3;
    a0 += __shfl_xor(a0, 16); a0 += __shfl_xor(a0, 32);
    a1 += __shfl_xor(a1, 16); a1 += __shfl_xor(a1, 32);
    a2 += __shfl_xor(a2, 16); a2 += __shfl_xor(a2, 32);
    a3 += __shfl_xor(a3, 16); a3 += __shfl_xor(a3, 32);

    const float inv = 1.0f / fmaxf((float)(e - b), 1.0f);
    const int f0 = q * 4;
    float4 rv = *(const float4*)(r1 + (size_t)node * 64 + f0);
    float acc[4] = {a0, a1, a2, a3};
    float rr[4]  = {rv.x, rv.y, rv.z, rv.w};
    float l0 = 0.f, l1 = 0.f;
    #pragma unroll
    for (int i = 0; i < 4; ++i) {
        int f = f0 + i;
        float pre = acc[i] * inv + b2l[f] + rr[i];
        float s   = g2[f] * rsqrtf(v2[f] + BN_EPS);
        float h2  = fmaxf((pre - m2[f]) * s + be2[f], 0.0f);
        l0 = fmaf(h2, Wc[f * 2 + 0], l0);
        l1 = fmaf(h2, Wc[f * 2 + 1], l1);
    }
    #pragma unroll
    for (int off = 8; off > 0; off >>= 1) {
        l0 += __shfl_xor(l0, off);
        l1 += __shfl_xor(l1, off);
    }
    if (lane == 0) {
        out[(size_t)node * 2 + 0] = l0 + bc[0];
        out[(size_t)node * 2 + 1] = l1 + bc[1];
    }
}

// ---------------------------------------------------------------------------
extern "C" void kernel_launch(void* const* d_in, const int* in_sizes, int n_in,
                              void* d_out, int out_size, void* d_ws, size_t ws_size,
                              hipStream_t stream)
{
    const float* x    = (const float*)d_in[0];
    const int*   eidx = (const int*)d_in[1];   // [2, E]: row 0 = src, row 1 = dst
    const float* W1l  = (const float*)d_in[2];
    const float* b1l  = (const float*)d_in[3];
    const float* W1r  = (const float*)d_in[4];
    const float* W2l  = (const float*)d_in[5];
    const float* b2l  = (const float*)d_in[6];
    const float* W2r  = (const float*)d_in[7];
    const float* g1   = (const float*)d_in[8];
    const float* be1  = (const float*)d_in[9];
    const float* m1   = (const float*)d_in[10];
    const float* v1   = (const float*)d_in[11];
    const float* g2   = (const float*)d_in[12];
    const float* be2  = (const float*)d_in[13];
    const float* m2   = (const float*)d_in[14];
    const float* v2   = (const float*)d_in[15];
    const float* Wc   = (const float*)d_in[16];
    const float* bc   = (const float*)d_in[17];
    float* out = (float*)d_out;

    const int* src = eidx;
    const int* dst = eidx + N_EDGES;

    // ---- workspace layout ----
    char* ws = (char*)d_ws;
    size_t off = 0;
    auto alloc = [&](size_t bytes) { void* p = ws + off; off = (off + bytes + 255) & ~(size_t)255; return p; };
    int* bucketTotal  = (int*)alloc((size_t)NB * 4);
    int* bucketStart  = (int*)alloc((size_t)(NB + 1) * 4);
    int* perBlockBase = (int*)alloc((size_t)BIN_BLOCKS * NB * 4);
    unsigned int* binned = (unsigned int*)alloc((size_t)N_EDGES * 4);
    int* sortedSrc    = (int*)alloc((size_t)N_EDGES * 4);
    int* rowStart     = (int*)alloc((size_t)(N_NODES + 1) * 4);
    unsigned short* Wf1  = (unsigned short*)alloc(128 * 128 * 2);
    unsigned short* Wf2  = (unsigned short*)alloc(128 * 128 * 2);
    unsigned short* Abuf = (unsigned short*)alloc((size_t)N_NODES * 128 * 2);
    unsigned short* t1   = (unsigned short*)alloc((size_t)N_NODES * 64 * 2);
    float* r1            = (float*)alloc((size_t)N_NODES * 64 * 4);

    const int gemmGrid     = (N_NODES + 63) / 64;            // 1563
    const int nodeWaveGrid = (N_NODES * 64 + 255) / 256;     // 25000

    // ---- prep ----
    prep_wfrag<<<16, 256, 0, stream>>>(W1l, W1r, W2l, W2r, Wf1, Wf2);
    cast_x<<<(N_NODES * 16 + 255) / 256, 256, 0, stream>>>(x, Abuf);

    // ---- counting sort of edges by dst ----
    hipMemsetAsync(bucketTotal, 0, (size_t)NB * 4, stream);
    bin_count  <<<BIN_BLOCKS, 256, 0, stream>>>(dst, bucketTotal, perBlockBase);
    bucket_scan<<<1, 1024, 0, stream>>>(bucketTotal, bucketStart);
    bin_write  <<<BIN_BLOCKS, 256, 0, stream>>>(src, dst, bucketStart, perBlockBase, binned);
    bucket_sort<<<NB, 256, 0, stream>>>(binned, bucketStart, sortedSrc, rowStart);

    // ---- layer 1: mean (bf16, from bf16 x-half) -> Abuf cols [0,64) ----
    gather1_v2<<<nodeWaveGrid, 256, 0, stream>>>(rowStart, sortedSrc, Abuf);

    // ---- fused dense (MFMA): h1 internal -> t1 (bf16), r1 (fp32) ----
    gemm_fused_mfma<<<gemmGrid, 256, 0, stream>>>(
        Abuf, Wf1, Wf2, b1l, g1, be1, m1, v1, t1, r1);

    // ---- layer 2: gather t1 + fused BN2/ReLU/classifier -> out ----
    gather2_v2<<<nodeWaveGrid, 256, 0, stream>>>(
        t1, rowStart, sortedSrc, r1, b2l, g2, be2, m2, v2, Wc, bc, out);
}